// Round 8
// baseline (475.477 us; speedup 1.0000x reference)
//
#include <hip/hip_runtime.h>
#include <hip/hip_bf16.h>
#include <math.h>

#define B_  2
#define T_  2048
#define D_  512
#define H_  8
#define HD_ 64
#define FFN_ 2048
#define VOCAB_ 256
#define BT_ (B_*T_)
#define NC_ 32            // chunks per (b,h), chunk size 64
#define CENT_ 4160        // floats per chunk state: 64*64 S + 64 z

typedef __attribute__((ext_vector_type(8))) short short8;
typedef __attribute__((ext_vector_type(4))) float float4v;
typedef __hip_bfloat16 bf16;

// async 16B/lane global->LDS DMA (wave-uniform LDS base + lane*16)
__device__ __forceinline__ void load16_lds(const void* g, void* l) {
  __builtin_amdgcn_global_load_lds(
      (const __attribute__((address_space(1))) unsigned int*)g,
      (__attribute__((address_space(3))) unsigned int*)l,
      16, 0, 0);
}

// ---------------------------------------------------------------------------
// Embedding + sinusoidal positional concat; writes fp32 x and bf16 mirror xb
// ---------------------------------------------------------------------------
__global__ __launch_bounds__(512) void embed_pos_kernel(
    const int* __restrict__ tokens, const float* __restrict__ emb,
    float* __restrict__ x, bf16* __restrict__ xb)
{
  int bt = blockIdx.x;          // b*T + t
  int t  = bt & (T_ - 1);
  int j  = threadIdx.x;
  float val;
  if (j < 256) {
    int tok = tokens[bt];
    val = emb[tok * 256 + j];
  } else {
    int jj = (j - 256) & 127;
    float f = expf(-(float)(2 * jj) * (9.210340371976184f / 256.0f));
    float arg = (float)t * f;
    val = (j < 384) ? sinf(arg) : cosf(arg);
  }
  size_t off = (size_t)bt * D_ + j;
  x[off]  = val;
  xb[off] = __float2bfloat16(val);
}

// ---------------------------------------------------------------------------
// Transpose-cast: W fp32 [K,N] (layer slice via blockIdx.z) -> Wt bf16 [N,K]
// ---------------------------------------------------------------------------
__global__ __launch_bounds__(256) void transpose_cast_kernel(
    const float* __restrict__ W, bf16* __restrict__ Wt, int K, int N)
{
  __shared__ float t[32][33];
  int n0 = blockIdx.x * 32, k0 = blockIdx.y * 32;
  const float* Wl = W + (size_t)blockIdx.z * K * N;
  bf16* Wtl = Wt + (size_t)blockIdx.z * K * N;
  int tx = threadIdx.x & 31, ty = threadIdx.x >> 5;  // ty 0..7
#pragma unroll
  for (int r = 0; r < 4; ++r)
    t[ty + 8 * r][tx] = Wl[(size_t)(k0 + ty + 8 * r) * N + n0 + tx];
  __syncthreads();
#pragma unroll
  for (int r = 0; r < 4; ++r)
    Wtl[(size_t)(n0 + ty + 8 * r) * K + k0 + tx] = __float2bfloat16(t[tx][ty + 8 * r]);
}

// ---------------------------------------------------------------------------
// RF-fold weights: W'T[n,k] = s * sum_d W[k, h*64+d] * R_h[d, n&63]
// (folds the FAVOR random-feature matmul + 64^-0.25 scale into Wq/Wk).
// grid (h=8, kq=4, z=4), z = l*2+side. Output layout: bf16 [N=512 rows][K=512].
// ---------------------------------------------------------------------------
__global__ __launch_bounds__(256) void rf_fold_w_kernel(
    const float* __restrict__ Wq, const float* __restrict__ Wk,
    const float* __restrict__ rfs, bf16* __restrict__ WqT, bf16* __restrict__ WkT)
{
  int h = blockIdx.x, kq = blockIdx.y, z = blockIdx.z;
  int l = z >> 1, side = z & 1;
  const float* W = (side ? Wk : Wq) + (size_t)l * D_ * D_;
  bf16* WT = (side ? WkT : WqT) + (size_t)l * D_ * D_;
  const float* R = rfs + ((size_t)l * H_ + h) * 4096;   // R_h[d][j]
  __shared__ float Rl[64][64];
  int tid = threadIdx.x;
  for (int i = tid; i < 4096; i += 256) Rl[i >> 6][i & 63] = R[i];
  __syncthreads();
  int lane = tid & 63, grp = tid >> 6;                  // 0..3
  int k = kq * 128 + (grp & 1) * 64 + lane;
  int j0 = (grp >> 1) * 32;
  const float* Wrow = W + (size_t)k * D_ + h * 64;      // 64 floats (L1-cached)
  for (int jj = 0; jj < 32; ++jj) {
    int j = j0 + jj;
    float acc = 0.f;
#pragma unroll 8
    for (int d = 0; d < 64; ++d) acc += Wrow[d] * Rl[d][j];
    WT[(size_t)(h * 64 + j) * D_ + k] = __float2bfloat16(acc * 0.35355339059327373f);
  }
}

// ---------------------------------------------------------------------------
// RF-fold biases: b'[n] = s * sum_d b[h*64+d] * R_h[d, n&63]. grid 4 = l*2+side.
// ---------------------------------------------------------------------------
__global__ __launch_bounds__(256) void rf_fold_b_kernel(
    const float* __restrict__ bq, const float* __restrict__ bk,
    const float* __restrict__ rfs, float* __restrict__ bqf, float* __restrict__ bkf)
{
  int z = blockIdx.x;
  int l = z >> 1, side = z & 1;
  const float* b = (side ? bk : bq) + l * D_;
  float* bo = (side ? bkf : bqf) + l * D_;
  for (int n = threadIdx.x; n < D_; n += 256) {
    int h = n >> 6, j = n & 63;
    const float* R = rfs + ((size_t)l * H_ + h) * 4096;
    float acc = 0.f;
    for (int d = 0; d < 64; ++d) acc += b[h * 64 + d] * R[d * 64 + j];
    bo[n] = acc * 0.35355339059327373f;
  }
}

// ---------------------------------------------------------------------------
// MFMA GEMM core: acc += A[row0:+128, :kr*32] @ Bt[col0:+128, :kr*32]^T
// 128x128 tile, BK=32, 4 waves (2x2), global_load_lds staging (m97 loop).
// ---------------------------------------------------------------------------
__device__ __forceinline__ void mfma_core(
    const bf16* __restrict__ A, const bf16* __restrict__ Bt,
    int strideK, int kr, int row0, int col0, float4v acc[4][4])
{
  __shared__ short Al[128 * 32];   // [row][k], k contiguous
  __shared__ short Bl[128 * 32];
  int tid = threadIdx.x;
  int lane = tid & 63, w = tid >> 6;
  int wm = (w >> 1) * 64, wn = (w & 1) * 64;
  int quad = lane >> 4, l16 = lane & 15;

  int r0 = 32 * w + (lane >> 2);
  int ks = (lane & 3) * 8;
  const short* gA0 = (const short*)A + (size_t)(row0 + r0) * strideK + ks;
  const short* gA1 = gA0 + (size_t)16 * strideK;
  const short* gB0 = (const short*)Bt + (size_t)(col0 + r0) * strideK + ks;
  const short* gB1 = gB0 + (size_t)16 * strideK;
  short* lA0 = Al + (32 * w) * 32;
  short* lA1 = Al + (32 * w + 16) * 32;
  short* lB0 = Bl + (32 * w) * 32;
  short* lB1 = Bl + (32 * w + 16) * 32;

  load16_lds(gA0, lA0);
  load16_lds(gA1, lA1);
  load16_lds(gB0, lB0);
  load16_lds(gB1, lB1);

  for (int kt = 0; kt < kr; ++kt) {
    __syncthreads();               // drains vmcnt -> tile kt in LDS
    short8 af[4], bfr[4];
#pragma unroll
    for (int mi = 0; mi < 4; ++mi)
      af[mi] = *(const short8*)&Al[(wm + mi * 16 + l16) * 32 + quad * 8];
#pragma unroll
    for (int ni = 0; ni < 4; ++ni)
      bfr[ni] = *(const short8*)&Bl[(wn + ni * 16 + l16) * 32 + quad * 8];
    __syncthreads();               // frags in regs; LDS reusable
    if (kt + 1 < kr) {             // next-tile DMA overlaps MFMA
      int o = (kt + 1) * 32;
      load16_lds(gA0 + o, lA0);
      load16_lds(gA1 + o, lA1);
      load16_lds(gB0 + o, lB0);
      load16_lds(gB1 + o, lB1);
    }
#pragma unroll
    for (int mi = 0; mi < 4; ++mi)
#pragma unroll
      for (int ni = 0; ni < 4; ++ni)
        acc[mi][ni] = __builtin_amdgcn_mfma_f32_16x16x32_bf16(
            af[mi], bfr[ni], acc[mi][ni], 0, 0, 0);
  }
}

// ---------------------------------------------------------------------------
// Generic GEMM: C = act(A @ Bt^T + bias). mode 0: fp32. mode 1: gelu->bf16.
// ---------------------------------------------------------------------------
__global__ __launch_bounds__(256) void gemm_mfma(
    const bf16* __restrict__ A, const bf16* __restrict__ Bt,
    const float* __restrict__ bias, void* __restrict__ Cout,
    int M, int N, int K, int mode)
{
  int lane = threadIdx.x & 63, w = threadIdx.x >> 6;
  int wm = (w >> 1) * 64, wn = (w & 1) * 64;
  int quad = lane >> 4, l16 = lane & 15;
  int row0 = blockIdx.y * 128, col0 = blockIdx.x * 128;
  float4v acc[4][4] = {};
  mfma_core(A, Bt, K, K >> 5, row0, col0, acc);
#pragma unroll
  for (int mi = 0; mi < 4; ++mi) {
#pragma unroll
    for (int ni = 0; ni < 4; ++ni) {
      int j = col0 + wn + ni * 16 + l16;
      float bj = bias[j];
#pragma unroll
      for (int r = 0; r < 4; ++r) {
        int i = row0 + wm + mi * 16 + quad * 4 + r;
        float v = acc[mi][ni][r] + bj;
        if (mode == 1) {
          v = 0.5f * v * (1.0f + erff(v * 0.7071067811865475f));
          ((bf16*)Cout)[(size_t)i * N + j] = __float2bfloat16(v);
        } else {
          ((float*)Cout)[(size_t)i * N + j] = v;
        }
      }
    }
  }
}

// ---------------------------------------------------------------------------
// Batched QKV GEMM: blockIdx.z = {q,k,v}. Q/K use RF-folded weights/biases.
// ---------------------------------------------------------------------------
__global__ __launch_bounds__(256) void gemm_qkv(
    const bf16* __restrict__ A, const bf16* __restrict__ wT,
    const float* __restrict__ bqf, const float* __restrict__ bkf,
    const float* __restrict__ bv, float* __restrict__ outb, int l)
{
  int z = blockIdx.z;
  const bf16* Bt = wT + ((size_t)z * 2 + l) * D_ * D_;
  const float* bias = (z == 0 ? bqf : (z == 1 ? bkf : bv)) + l * D_;
  float* Cout = outb + (size_t)z * BT_ * D_;
  int lane = threadIdx.x & 63, w = threadIdx.x >> 6;
  int wm = (w >> 1) * 64, wn = (w & 1) * 64;
  int quad = lane >> 4, l16 = lane & 15;
  int row0 = blockIdx.y * 128, col0 = blockIdx.x * 128;
  float4v acc[4][4] = {};
  mfma_core(A, Bt, D_, D_ >> 5, row0, col0, acc);
#pragma unroll
  for (int mi = 0; mi < 4; ++mi) {
#pragma unroll
    for (int ni = 0; ni < 4; ++ni) {
      int j = col0 + wn + ni * 16 + l16;
      float bj = bias[j];
#pragma unroll
      for (int r = 0; r < 4; ++r) {
        int i = row0 + wm + mi * 16 + quad * 4 + r;
        Cout[(size_t)i * D_ + j] = acc[mi][ni][r] + bj;
      }
    }
  }
}

// ---------------------------------------------------------------------------
// Split-K GEMM: P[s][M][N] = A[:, s*KS:(s+1)*KS] @ slice. s = blockIdx.z.
// ---------------------------------------------------------------------------
__global__ __launch_bounds__(256) void gemm_splitk(
    const bf16* __restrict__ A, const bf16* __restrict__ Bt,
    float* __restrict__ P, int M, int N, int K, int KS)
{
  int s = blockIdx.z;
  int lane = threadIdx.x & 63, w = threadIdx.x >> 6;
  int wm = (w >> 1) * 64, wn = (w & 1) * 64;
  int quad = lane >> 4, l16 = lane & 15;
  int row0 = blockIdx.y * 128, col0 = blockIdx.x * 128;
  float4v acc[4][4] = {};
  mfma_core((const bf16*)((const short*)A + s * KS),
            (const bf16*)((const short*)Bt + s * KS),
            K, KS >> 5, row0, col0, acc);
  float* Ps = P + (size_t)s * M * N;
#pragma unroll
  for (int mi = 0; mi < 4; ++mi) {
#pragma unroll
    for (int ni = 0; ni < 4; ++ni) {
      int j = col0 + wn + ni * 16 + l16;
#pragma unroll
      for (int r = 0; r < 4; ++r) {
        int i = row0 + wm + mi * 16 + quad * 4 + r;
        Ps[(size_t)i * N + j] = acc[mi][ni][r];
      }
    }
  }
}

// ---------------------------------------------------------------------------
// C[idx..idx+3] = bias + sum over 4 split partials (float4 vectorized)
// ---------------------------------------------------------------------------
__global__ __launch_bounds__(256) void reduce4_bias_kernel(
    const float* __restrict__ P, const float* __restrict__ bias,
    float* __restrict__ C, int MN, int N)
{
  int idx = (blockIdx.x * 256 + threadIdx.x) * 4;
  float4 s0 = *(const float4*)&P[idx];
  float4 s1 = *(const float4*)&P[idx + MN];
  float4 s2 = *(const float4*)&P[idx + 2 * MN];
  float4 s3 = *(const float4*)&P[idx + 3 * MN];
  float4 b  = *(const float4*)&bias[idx & (N - 1)];
  float4 r;
  r.x = s0.x + s1.x + s2.x + s3.x + b.x;
  r.y = s0.y + s1.y + s2.y + s3.y + b.y;
  r.z = s0.z + s1.z + s2.z + s3.z + b.z;
  r.w = s0.w + s1.w + s2.w + s3.w + b.w;
  *(float4*)&C[idx] = r;
}

// ---------------------------------------------------------------------------
// FAVOR exp pass on RF-folded q'/k': out = exp(v - ||row||^2/128)
// (||xp||^2 = ||xp@R||^2/64 since R R^T = 64 I). One wave per head-row.
// ---------------------------------------------------------------------------
__global__ __launch_bounds__(256) void favor_exp_kernel(
    float* __restrict__ qb, float* __restrict__ kb)
{
  int wv = threadIdx.x >> 6;
  int u = blockIdx.x * 4 + wv;      // 0 .. 2*BT*H-1
  int m = threadIdx.x & 63;
  int side = u & 1;
  int row = u >> 1;
  float* x = side ? kb : qb;
  size_t off = (size_t)row * 64;
  float v = x[off + m];
  float sq = v * v;
#pragma unroll
  for (int o = 1; o < 64; o <<= 1) sq += __shfl_xor(sq, o, 64);
  x[off + m] = __expf(v - sq * (1.0f / 128.0f));
}

// ---------------------------------------------------------------------------
// Pass 1: per-chunk sums (chunks 0..30 per bh)
// ---------------------------------------------------------------------------
__global__ __launch_bounds__(256) void chunk_sum_kernel(
    const float* __restrict__ kf, const float* __restrict__ v,
    float* __restrict__ buf)
{
  int bh = blockIdx.x / 31;
  int c  = blockIdx.x % 31;
  int b = bh >> 3, h = bh & 7;
  __shared__ float Ks[64][68], Vs[64][68];
  int tid = threadIdx.x;
  int d = tid & 63, g = tid >> 6;
  for (int t4 = 0; t4 < 64; t4 += 4) {
    int t = t4 + g;
    size_t off = ((size_t)(b * T_ + c * 64 + t) * D_) + h * 64 + d;
    Ks[t][d] = kf[off];
    Vs[t][d] = v[off];
  }
  __syncthreads();
  float acc[16];
#pragma unroll
  for (int i = 0; i < 16; ++i) acc[i] = 0.f;
  for (int t = 0; t < 64; ++t) {
    float vv = Vs[t][d];
#pragma unroll
    for (int i = 0; i < 16; ++i) acc[i] += Ks[t][g * 16 + i] * vv;
  }
  size_t bo = (size_t)(bh * 31 + c) * CENT_;
#pragma unroll
  for (int i = 0; i < 16; ++i) buf[bo + (size_t)(g * 16 + i) * 64 + d] = acc[i];
  if (tid < 64) {
    float zz = 0.f;
    for (int t = 0; t < 64; ++t) zz += Ks[t][tid];
    buf[bo + 4096 + tid] = zz;
  }
}

// ---------------------------------------------------------------------------
// Pass 2: inclusive scan over 31 chunk states per (b,h)
// ---------------------------------------------------------------------------
__global__ __launch_bounds__(256) void chunk_prefix_kernel(float* __restrict__ buf)
{
  int bh = blockIdx.x / 17;
  int grp = blockIdx.x % 17;
  int e = grp * 256 + threadIdx.x;
  if (e >= CENT_) return;
  size_t base = (size_t)bh * 31 * CENT_ + e;
  float run = 0.f;
  for (int c = 0; c < 31; ++c) {
    run += buf[base + (size_t)c * CENT_];
    buf[base + (size_t)c * CENT_] = run;
  }
}

// ---------------------------------------------------------------------------
// Pass 3: per-chunk attention (pad 65: lane-row reads 2-way, conflict-free)
// ---------------------------------------------------------------------------
__global__ __launch_bounds__(256) void chunk_attn_kernel(
    const float* __restrict__ qf, const float* __restrict__ kf,
    const float* __restrict__ v, const float* __restrict__ buf,
    float* __restrict__ out)
{
  int bh = blockIdx.x >> 5;
  int c  = blockIdx.x & 31;
  int b = bh >> 3, h = bh & 7;
  __shared__ float Qs[64][65], Ks[64][65], Vs[64][65];  // Ks reused for A
  __shared__ float den[64];
  int tid = threadIdx.x;
  int d = tid & 63, g = tid >> 6;
  for (int t4 = 0; t4 < 64; t4 += 4) {
    int t = t4 + g;
    size_t off = ((size_t)(b * T_ + c * 64 + t) * D_) + h * 64 + d;
    Qs[t][d] = qf[off];
    Ks[t][d] = kf[off];
    Vs[t][d] = v[off];
  }
  __syncthreads();
  float a[16];
  {
    int i = d;
#pragma unroll
    for (int jj = 0; jj < 16; ++jj) a[jj] = 0.f;
    for (int m = 0; m < 64; ++m) {
      float qv = Qs[i][m];
#pragma unroll
      for (int jj = 0; jj < 16; ++jj) a[jj] += qv * Ks[g * 16 + jj][m];
    }
  }
  __syncthreads();
  {
    int i = d;
#pragma unroll
    for (int jj = 0; jj < 16; ++jj) {
      int j = g * 16 + jj;
      Ks[i][j] = (j <= i) ? a[jj] : 0.f;
    }
  }
  __syncthreads();
  const float* S0 = buf + (size_t)(bh * 31 + (c - 1)) * CENT_;  // valid if c>0
  if (tid < 64) {
    int i = tid;
    float dn = 0.f;
    for (int j = 0; j < 64; ++j) dn += Ks[i][j];
    if (c > 0) {
      const float* z0 = S0 + 4096;
      for (int m = 0; m < 64; ++m) dn += Qs[i][m] * z0[m];
    }
    den[i] = dn;
  }
  float acc[16];
#pragma unroll
  for (int ii = 0; ii < 16; ++ii) acc[ii] = 0.f;
  for (int j = 0; j < 64; ++j) {
    float vv = Vs[j][d];
#pragma unroll
    for (int ii = 0; ii < 16; ++ii) acc[ii] += Ks[g * 16 + ii][j] * vv;
  }
  if (c > 0) {
    for (int m = 0; m < 64; ++m) {
      float s0 = S0[(size_t)m * 64 + d];
#pragma unroll
      for (int ii = 0; ii < 16; ++ii) acc[ii] += Qs[g * 16 + ii][m] * s0;
    }
  }
  __syncthreads();
#pragma unroll
  for (int ii = 0; ii < 16; ++ii) {
    int i = g * 16 + ii;
    size_t off = ((size_t)(b * T_ + c * 64 + i) * D_) + h * 64 + d;
    out[off] = acc[ii] / (den[i] + 1e-16f);
  }
}

// ---------------------------------------------------------------------------
// x[row,:] += LayerNorm(a[row,:]) * g + b ; also writes bf16 mirror xb
// ---------------------------------------------------------------------------
__global__ __launch_bounds__(256) void ln_add_kernel(
    float* __restrict__ x, bf16* __restrict__ xb, const float* __restrict__ a,
    const float* __restrict__ g, const float* __restrict__ bta)
{
  int row = blockIdx.x;
  int tid = threadIdx.x;
  const float* ar = a + (size_t)row * D_;
  float v0 = ar[tid], v1 = ar[tid + 256];
  __shared__ float red[4];
  float w = v0 + v1;
  for (int o = 32; o > 0; o >>= 1) w += __shfl_down(w, o, 64);
  if ((tid & 63) == 0) red[tid >> 6] = w;
  __syncthreads();
  float mu = (red[0] + red[1] + red[2] + red[3]) * (1.f / 512.f);
  float d0 = v0 - mu, d1 = v1 - mu;
  __syncthreads();
  w = d0 * d0 + d1 * d1;
  for (int o = 32; o > 0; o >>= 1) w += __shfl_down(w, o, 64);
  if ((tid & 63) == 0) red[tid >> 6] = w;
  __syncthreads();
  float var = (red[0] + red[1] + red[2] + red[3]) * (1.f / 512.f);
  float rs = rsqrtf(var + 1e-5f);
  size_t xoff = (size_t)row * D_;
  float n0 = x[xoff + tid]       + d0 * rs * g[tid]       + bta[tid];
  float n1 = x[xoff + tid + 256] + d1 * rs * g[tid + 256] + bta[tid + 256];
  x[xoff + tid]        = n0;
  x[xoff + tid + 256]  = n1;
  xb[xoff + tid]       = __float2bfloat16(n0);
  xb[xoff + tid + 256] = __float2bfloat16(n1);
}

// ---------------------------------------------------------------------------
extern "C" void kernel_launch(void* const* d_in, const int* in_sizes, int n_in,
                              void* d_out, int out_size, void* d_ws, size_t ws_size,
                              hipStream_t stream) {
  const int*   tokens = (const int*)  d_in[0];
  const float* emb    = (const float*)d_in[1];
  const float* Wq     = (const float*)d_in[2];
  const float* bq     = (const float*)d_in[3];
  const float* Wk     = (const float*)d_in[4];
  const float* bk     = (const float*)d_in[5];
  const float* Wv     = (const float*)d_in[6];
  const float* bv     = (const float*)d_in[7];
  const float* rfs    = (const float*)d_in[8];
  const float* ln1g   = (const float*)d_in[9];
  const float* ln1b   = (const float*)d_in[10];
  const float* ln2g   = (const float*)d_in[11];
  const float* ln2b   = (const float*)d_in[12];
  const float* WU     = (const float*)d_in[13];
  const float* bU     = (const float*)d_in[14];
  const float* WV     = (const float*)d_in[15];
  const float* bV     = (const float*)d_in[16];
  const float* Wout   = (const float*)d_in[17];
  const float* bout   = (const float*)d_in[18];
  float* out = (float*)d_out;

  const size_t R = (size_t)BT_ * D_;          // 2,097,152 floats (8 MB)
  float* ws = (float*)d_ws;
  float* x  = ws + 0 * R;
  float* ab = ws + 1 * R;
  float* qb = ws + 2 * R;
  float* kb = ws + 3 * R;
  float* vb = ws + 4 * R;
  float* sb = ws + 5 * R;                     // chunk states (7.9 MB)
  bf16*  xb = (bf16*)(ws + 6 * R);            // R bf16 = 4 MB
  bf16*  hb = (bf16*)qb;                      // FFN hidden bf16 aliases qb+kb
  float* pb = ws + 16 * R;                    // split-K partials (<=32 MB)
  // transposed bf16 weights
  bf16* wT    = (bf16*)(ws + 6 * R + R / 2);
  bf16* WqT   = wT;                            // [L][D][D]  (RF-folded)
  bf16* WkT   = WqT + (size_t)2 * D_ * D_;     // (RF-folded)
  bf16* WvT   = WkT + (size_t)2 * D_ * D_;
  bf16* WUT   = WvT + (size_t)2 * D_ * D_;     // [L][FFN][D]
  bf16* WVT   = WUT + (size_t)2 * D_ * FFN_;   // [L][D][FFN]
  bf16* WoutT = WVT + (size_t)2 * D_ * FFN_;   // [VOCAB][D]
  float* bqf  = (float*)(WoutT + (size_t)VOCAB_ * D_);  // [L][D] folded bias
  float* bkf  = bqf + 2 * D_;

  // ---- weight prep ----
  rf_fold_w_kernel<<<dim3(8, 4, 4), 256, 0, stream>>>(Wq, Wk, rfs, WqT, WkT);
  rf_fold_b_kernel<<<4, 256, 0, stream>>>(bq, bk, rfs, bqf, bkf);
  transpose_cast_kernel<<<dim3(D_/32,  D_/32,  2), 256, 0, stream>>>(Wv,   WvT,   D_,   D_);
  transpose_cast_kernel<<<dim3(FFN_/32,D_/32,  2), 256, 0, stream>>>(WU,   WUT,   D_,   FFN_);
  transpose_cast_kernel<<<dim3(D_/32,  FFN_/32,2), 256, 0, stream>>>(WV,   WVT,   FFN_, D_);
  transpose_cast_kernel<<<dim3(VOCAB_/32, D_/32,1), 256, 0, stream>>>(Wout, WoutT, D_,  VOCAB_);

  embed_pos_kernel<<<BT_, 512, 0, stream>>>(tokens, emb, x, xb);

  for (int l = 0; l < 2; ++l) {
    // batched QKV (q,k RF-folded): one launch, z = {q,k,v}, 384 blocks
    gemm_qkv<<<dim3(D_/128, BT_/128, 3), 256, 0, stream>>>(
        xb, wT, bqf, bkf, bv, qb, l);

    favor_exp_kernel<<<2 * BT_ * H_ / 4, 256, 0, stream>>>(qb, kb);

    chunk_sum_kernel<<<16 * 31, 256, 0, stream>>>(kb, vb, sb);
    chunk_prefix_kernel<<<16 * 17, 256, 0, stream>>>(sb);
    chunk_attn_kernel<<<16 * NC_, 256, 0, stream>>>(qb, kb, vb, sb, ab);

    ln_add_kernel<<<BT_, 256, 0, stream>>>(x, xb, ab, ln1g + l*D_, ln1b + l*D_);

    gemm_mfma<<<dim3(FFN_/128, BT_/128), 256, 0, stream>>>(
        xb, WUT + (size_t)l*D_*FFN_, bU + l*FFN_, hb, BT_, FFN_, D_, 1);

    // FFN2 split-K: K=2048 -> 4 x 512, then reduce + bias
    gemm_splitk<<<dim3(D_/128, BT_/128, 4), 256, 0, stream>>>(
        hb, WVT + (size_t)l*FFN_*D_, pb, BT_, D_, FFN_, FFN_/4);
    reduce4_bias_kernel<<<(BT_*D_)/1024, 256, 0, stream>>>(
        pb, bV + l*D_, ab, BT_*D_, D_);

    ln_add_kernel<<<BT_, 256, 0, stream>>>(x, xb, ab, ln2g + l*D_, ln2b + l*D_);
  }

  // Wout split-K: K=512 -> 4 x 128, then reduce + bias
  gemm_splitk<<<dim3(VOCAB_/128, BT_/128, 4), 256, 0, stream>>>(
      xb, WoutT, pb, BT_, VOCAB_, D_, D_/4);
  reduce4_bias_kernel<<<(BT_*VOCAB_)/1024, 256, 0, stream>>>(
      pb, bout, out, BT_*VOCAB_, VOCAB_);
}

// Round 9
// 415.912 us; speedup vs baseline: 1.1432x; 1.1432x over previous
//
#include <hip/hip_runtime.h>
#include <hip/hip_bf16.h>
#include <math.h>

#define B_  2
#define T_  2048
#define D_  512
#define H_  8
#define HD_ 64
#define FFN_ 2048
#define VOCAB_ 256
#define BT_ (B_*T_)
#define NC_ 32            // chunks per (b,h), chunk size 64
#define CENT_ 4160        // floats per chunk state: 64*64 S + 64 z

typedef __attribute__((ext_vector_type(8))) short short8;
typedef __attribute__((ext_vector_type(4))) float float4v;
typedef __hip_bfloat16 bf16;

// async 16B/lane global->LDS DMA (wave-uniform LDS base + lane*16)
__device__ __forceinline__ void load16_lds(const void* g, void* l) {
  __builtin_amdgcn_global_load_lds(
      (const __attribute__((address_space(1))) unsigned int*)g,
      (__attribute__((address_space(3))) unsigned int*)l,
      16, 0, 0);
}

// ---------------------------------------------------------------------------
// Embedding + sinusoidal positional concat; writes fp32 x and bf16 mirror xb
// ---------------------------------------------------------------------------
__global__ __launch_bounds__(512) void embed_pos_kernel(
    const int* __restrict__ tokens, const float* __restrict__ emb,
    float* __restrict__ x, bf16* __restrict__ xb)
{
  int bt = blockIdx.x;          // b*T + t
  int t  = bt & (T_ - 1);
  int j  = threadIdx.x;
  float val;
  if (j < 256) {
    int tok = tokens[bt];
    val = emb[tok * 256 + j];
  } else {
    int jj = (j - 256) & 127;
    float f = expf(-(float)(2 * jj) * (9.210340371976184f / 256.0f));
    float arg = (float)t * f;
    val = (j < 384) ? sinf(arg) : cosf(arg);
  }
  size_t off = (size_t)bt * D_ + j;
  x[off]  = val;
  xb[off] = __float2bfloat16(val);
}

// ---------------------------------------------------------------------------
// Transpose-cast: W fp32 [K,N] (layer slice via blockIdx.z) -> Wt bf16 [N,K]
// ---------------------------------------------------------------------------
__global__ __launch_bounds__(256) void transpose_cast_kernel(
    const float* __restrict__ W, bf16* __restrict__ Wt, int K, int N)
{
  __shared__ float t[32][33];
  int n0 = blockIdx.x * 32, k0 = blockIdx.y * 32;
  const float* Wl = W + (size_t)blockIdx.z * K * N;
  bf16* Wtl = Wt + (size_t)blockIdx.z * K * N;
  int tx = threadIdx.x & 31, ty = threadIdx.x >> 5;  // ty 0..7
#pragma unroll
  for (int r = 0; r < 4; ++r)
    t[ty + 8 * r][tx] = Wl[(size_t)(k0 + ty + 8 * r) * N + n0 + tx];
  __syncthreads();
#pragma unroll
  for (int r = 0; r < 4; ++r)
    Wtl[(size_t)(n0 + ty + 8 * r) * K + k0 + tx] = __float2bfloat16(t[tx][ty + 8 * r]);
}

// ---------------------------------------------------------------------------
// RF-fold weights, LDS-staged: W'T[h*64+j, k] = s * sum_d W[k, h*64+d] R_h[d,j]
// grid (h=8, kq=4, z=4), z = l*2+side. Stage W-block (128 k x 64 d) and R
// (64x64) in LDS; lane=k padded 65 -> conflict-free; R read is broadcast.
// ---------------------------------------------------------------------------
__global__ __launch_bounds__(256) void rf_fold_w_kernel(
    const float* __restrict__ Wq, const float* __restrict__ Wk,
    const float* __restrict__ rfs, bf16* __restrict__ WqT, bf16* __restrict__ WkT)
{
  int h = blockIdx.x, kq = blockIdx.y, z = blockIdx.z;
  int l = z >> 1, side = z & 1;
  const float* W = (side ? Wk : Wq) + (size_t)l * D_ * D_;
  bf16* WT = (side ? WkT : WqT) + (size_t)l * D_ * D_;
  const float* Rg = rfs + ((size_t)l * H_ + h) * 4096;   // R_h[d][j]
  __shared__ float Rl[64][65];
  __shared__ float Ws[128][65];
  int tid = threadIdx.x;
  for (int i = tid; i < 1024; i += 256) {        // R: 1024 float4
    float4 v4 = ((const float4*)Rg)[i];
    int d = i >> 4, j0 = (i & 15) * 4;
    Rl[d][j0] = v4.x; Rl[d][j0+1] = v4.y; Rl[d][j0+2] = v4.z; Rl[d][j0+3] = v4.w;
  }
  for (int i = tid; i < 2048; i += 256) {        // W: 128 rows x 16 float4
    int r = i >> 4, c0 = (i & 15) * 4;
    float4 v4 = *(const float4*)&W[(size_t)(kq * 128 + r) * D_ + h * 64 + c0];
    Ws[r][c0] = v4.x; Ws[r][c0+1] = v4.y; Ws[r][c0+2] = v4.z; Ws[r][c0+3] = v4.w;
  }
  __syncthreads();
  int lane = tid & 63, w = tid >> 6;             // wave w: j in [16w,16w+16)
  for (int kh = 0; kh < 2; ++kh) {               // k = kh*64 + lane
    int kk = kh * 64 + lane;
#pragma unroll 1
    for (int jj = 0; jj < 16; ++jj) {
      int j = w * 16 + jj;
      float acc = 0.f;
#pragma unroll 16
      for (int d = 0; d < 64; ++d) acc += Ws[kk][d] * Rl[d][j];
      WT[(size_t)(h * 64 + j) * D_ + kq * 128 + kk] =
          __float2bfloat16(acc * 0.35355339059327373f);
    }
  }
}

// ---------------------------------------------------------------------------
// RF-fold biases: b'[n] = s * sum_d b[h*64+d] * R_h[d, n&63]. grid 4 = l*2+side.
// ---------------------------------------------------------------------------
__global__ __launch_bounds__(256) void rf_fold_b_kernel(
    const float* __restrict__ bq, const float* __restrict__ bk,
    const float* __restrict__ rfs, float* __restrict__ bqf, float* __restrict__ bkf)
{
  int z = blockIdx.x;
  int l = z >> 1, side = z & 1;
  const float* b = (side ? bk : bq) + l * D_;
  float* bo = (side ? bkf : bqf) + l * D_;
  for (int n = threadIdx.x; n < D_; n += 256) {
    int h = n >> 6, j = n & 63;
    const float* R = rfs + ((size_t)l * H_ + h) * 4096;
    float acc = 0.f;
    for (int d = 0; d < 64; ++d) acc += b[h * 64 + d] * R[d * 64 + j];
    bo[n] = acc * 0.35355339059327373f;
  }
}

// ---------------------------------------------------------------------------
// MFMA GEMM core: acc += A[row0:+128, :kr*32] @ Bt[col0:+128, :kr*32]^T
// 128x128 tile, BK=32, 4 waves (2x2), global_load_lds staging (m97 loop).
// ---------------------------------------------------------------------------
__device__ __forceinline__ void mfma_core(
    const bf16* __restrict__ A, const bf16* __restrict__ Bt,
    int strideK, int kr, int row0, int col0, float4v acc[4][4])
{
  __shared__ short Al[128 * 32];   // [row][k], k contiguous
  __shared__ short Bl[128 * 32];
  int tid = threadIdx.x;
  int lane = tid & 63, w = tid >> 6;
  int wm = (w >> 1) * 64, wn = (w & 1) * 64;
  int quad = lane >> 4, l16 = lane & 15;

  int r0 = 32 * w + (lane >> 2);
  int ks = (lane & 3) * 8;
  const short* gA0 = (const short*)A + (size_t)(row0 + r0) * strideK + ks;
  const short* gA1 = gA0 + (size_t)16 * strideK;
  const short* gB0 = (const short*)Bt + (size_t)(col0 + r0) * strideK + ks;
  const short* gB1 = gB0 + (size_t)16 * strideK;
  short* lA0 = Al + (32 * w) * 32;
  short* lA1 = Al + (32 * w + 16) * 32;
  short* lB0 = Bl + (32 * w) * 32;
  short* lB1 = Bl + (32 * w + 16) * 32;

  load16_lds(gA0, lA0);
  load16_lds(gA1, lA1);
  load16_lds(gB0, lB0);
  load16_lds(gB1, lB1);

  for (int kt = 0; kt < kr; ++kt) {
    __syncthreads();               // drains vmcnt -> tile kt in LDS
    short8 af[4], bfr[4];
#pragma unroll
    for (int mi = 0; mi < 4; ++mi)
      af[mi] = *(const short8*)&Al[(wm + mi * 16 + l16) * 32 + quad * 8];
#pragma unroll
    for (int ni = 0; ni < 4; ++ni)
      bfr[ni] = *(const short8*)&Bl[(wn + ni * 16 + l16) * 32 + quad * 8];
    __syncthreads();               // frags in regs; LDS reusable
    if (kt + 1 < kr) {             // next-tile DMA overlaps MFMA
      int o = (kt + 1) * 32;
      load16_lds(gA0 + o, lA0);
      load16_lds(gA1 + o, lA1);
      load16_lds(gB0 + o, lB0);
      load16_lds(gB1 + o, lB1);
    }
#pragma unroll
    for (int mi = 0; mi < 4; ++mi)
#pragma unroll
      for (int ni = 0; ni < 4; ++ni)
        acc[mi][ni] = __builtin_amdgcn_mfma_f32_16x16x32_bf16(
            af[mi], bfr[ni], acc[mi][ni], 0, 0, 0);
  }
}

// ---------------------------------------------------------------------------
// Generic GEMM: C = act(A @ Bt^T + bias). mode 0: fp32. mode 1: gelu->bf16.
// ---------------------------------------------------------------------------
__global__ __launch_bounds__(256) void gemm_mfma(
    const bf16* __restrict__ A, const bf16* __restrict__ Bt,
    const float* __restrict__ bias, void* __restrict__ Cout,
    int M, int N, int K, int mode)
{
  int lane = threadIdx.x & 63, w = threadIdx.x >> 6;
  int wm = (w >> 1) * 64, wn = (w & 1) * 64;
  int quad = lane >> 4, l16 = lane & 15;
  int row0 = blockIdx.y * 128, col0 = blockIdx.x * 128;
  float4v acc[4][4] = {};
  mfma_core(A, Bt, K, K >> 5, row0, col0, acc);
#pragma unroll
  for (int mi = 0; mi < 4; ++mi) {
#pragma unroll
    for (int ni = 0; ni < 4; ++ni) {
      int j = col0 + wn + ni * 16 + l16;
      float bj = bias[j];
#pragma unroll
      for (int r = 0; r < 4; ++r) {
        int i = row0 + wm + mi * 16 + quad * 4 + r;
        float v = acc[mi][ni][r] + bj;
        if (mode == 1) {
          v = 0.5f * v * (1.0f + erff(v * 0.7071067811865475f));
          ((bf16*)Cout)[(size_t)i * N + j] = __float2bfloat16(v);
        } else {
          ((float*)Cout)[(size_t)i * N + j] = v;
        }
      }
    }
  }
}

// ---------------------------------------------------------------------------
// Batched QKV GEMM with fused FAVOR exp for q,k: blockIdx.z = {q,k,v}.
// Each wave's 64-column span is exactly one head -> ||row||^2 via 16-lane
// shfl_xor (1,2,4,8 stay within the quad); write exp(v - sq/128).
// ---------------------------------------------------------------------------
__global__ __launch_bounds__(256) void gemm_qkv(
    const bf16* __restrict__ A, const bf16* __restrict__ wT,
    const float* __restrict__ bqf, const float* __restrict__ bkf,
    const float* __restrict__ bv, float* __restrict__ outb, int l)
{
  int z = blockIdx.z;
  const bf16* Bt = wT + ((size_t)z * 2 + l) * D_ * D_;
  const float* bias = (z == 0 ? bqf : (z == 1 ? bkf : bv)) + l * D_;
  float* Cout = outb + (size_t)z * BT_ * D_;
  int lane = threadIdx.x & 63, w = threadIdx.x >> 6;
  int wm = (w >> 1) * 64, wn = (w & 1) * 64;
  int quad = lane >> 4, l16 = lane & 15;
  int row0 = blockIdx.y * 128, col0 = blockIdx.x * 128;
  float4v acc[4][4] = {};
  mfma_core(A, Bt, D_, D_ >> 5, row0, col0, acc);
  if (z < 2) {
#pragma unroll
    for (int mi = 0; mi < 4; ++mi) {
      float vres[4][4];            // [ni][r]
      float sq[4] = {0.f, 0.f, 0.f, 0.f};
#pragma unroll
      for (int ni = 0; ni < 4; ++ni) {
        int j = col0 + wn + ni * 16 + l16;
        float bj = bias[j];
#pragma unroll
        for (int r = 0; r < 4; ++r) {
          float v = acc[mi][ni][r] + bj;
          vres[ni][r] = v;
          sq[r] += v * v;
        }
      }
#pragma unroll
      for (int r = 0; r < 4; ++r) {
        float s = sq[r];
        s += __shfl_xor(s, 1, 64);
        s += __shfl_xor(s, 2, 64);
        s += __shfl_xor(s, 4, 64);
        s += __shfl_xor(s, 8, 64);
        sq[r] = s;
      }
#pragma unroll
      for (int ni = 0; ni < 4; ++ni) {
        int j = col0 + wn + ni * 16 + l16;
#pragma unroll
        for (int r = 0; r < 4; ++r) {
          int i = row0 + wm + mi * 16 + quad * 4 + r;
          Cout[(size_t)i * D_ + j] = __expf(vres[ni][r] - sq[r] * (1.0f / 128.0f));
        }
      }
    }
  } else {
#pragma unroll
    for (int mi = 0; mi < 4; ++mi) {
#pragma unroll
      for (int ni = 0; ni < 4; ++ni) {
        int j = col0 + wn + ni * 16 + l16;
        float bj = bias[j];
#pragma unroll
        for (int r = 0; r < 4; ++r) {
          int i = row0 + wm + mi * 16 + quad * 4 + r;
          Cout[(size_t)i * D_ + j] = acc[mi][ni][r] + bj;
        }
      }
    }
  }
}

// ---------------------------------------------------------------------------
// Split-K GEMM: P[s][M][N] = A[:, s*KS:(s+1)*KS] @ slice. s = blockIdx.z.
// ---------------------------------------------------------------------------
__global__ __launch_bounds__(256) void gemm_splitk(
    const bf16* __restrict__ A, const bf16* __restrict__ Bt,
    float* __restrict__ P, int M, int N, int K, int KS)
{
  int s = blockIdx.z;
  int lane = threadIdx.x & 63, w = threadIdx.x >> 6;
  int wm = (w >> 1) * 64, wn = (w & 1) * 64;
  int quad = lane >> 4, l16 = lane & 15;
  int row0 = blockIdx.y * 128, col0 = blockIdx.x * 128;
  float4v acc[4][4] = {};
  mfma_core((const bf16*)((const short*)A + s * KS),
            (const bf16*)((const short*)Bt + s * KS),
            K, KS >> 5, row0, col0, acc);
  float* Ps = P + (size_t)s * M * N;
#pragma unroll
  for (int mi = 0; mi < 4; ++mi) {
#pragma unroll
    for (int ni = 0; ni < 4; ++ni) {
      int j = col0 + wn + ni * 16 + l16;
#pragma unroll
      for (int r = 0; r < 4; ++r) {
        int i = row0 + wm + mi * 16 + quad * 4 + r;
        Ps[(size_t)i * N + j] = acc[mi][ni][r];
      }
    }
  }
}

// ---------------------------------------------------------------------------
// C[idx..idx+3] = bias + sum over 4 split partials (float4 vectorized)
// ---------------------------------------------------------------------------
__global__ __launch_bounds__(256) void reduce4_bias_kernel(
    const float* __restrict__ P, const float* __restrict__ bias,
    float* __restrict__ C, int MN, int N)
{
  int idx = (blockIdx.x * 256 + threadIdx.x) * 4;
  float4 s0 = *(const float4*)&P[idx];
  float4 s1 = *(const float4*)&P[idx + MN];
  float4 s2 = *(const float4*)&P[idx + 2 * MN];
  float4 s3 = *(const float4*)&P[idx + 3 * MN];
  float4 b  = *(const float4*)&bias[idx & (N - 1)];
  float4 r;
  r.x = s0.x + s1.x + s2.x + s3.x + b.x;
  r.y = s0.y + s1.y + s2.y + s3.y + b.y;
  r.z = s0.z + s1.z + s2.z + s3.z + b.z;
  r.w = s0.w + s1.w + s2.w + s3.w + b.w;
  *(float4*)&C[idx] = r;
}

// ---------------------------------------------------------------------------
// Pass 1: per-chunk sums (chunks 0..30 per bh)
// ---------------------------------------------------------------------------
__global__ __launch_bounds__(256) void chunk_sum_kernel(
    const float* __restrict__ kf, const float* __restrict__ v,
    float* __restrict__ buf)
{
  int bh = blockIdx.x / 31;
  int c  = blockIdx.x % 31;
  int b = bh >> 3, h = bh & 7;
  __shared__ float Ks[64][68], Vs[64][68];
  int tid = threadIdx.x;
  int d = tid & 63, g = tid >> 6;
  for (int t4 = 0; t4 < 64; t4 += 4) {
    int t = t4 + g;
    size_t off = ((size_t)(b * T_ + c * 64 + t) * D_) + h * 64 + d;
    Ks[t][d] = kf[off];
    Vs[t][d] = v[off];
  }
  __syncthreads();
  float acc[16];
#pragma unroll
  for (int i = 0; i < 16; ++i) acc[i] = 0.f;
  for (int t = 0; t < 64; ++t) {
    float vv = Vs[t][d];
#pragma unroll
    for (int i = 0; i < 16; ++i) acc[i] += Ks[t][g * 16 + i] * vv;
  }
  size_t bo = (size_t)(bh * 31 + c) * CENT_;
#pragma unroll
  for (int i = 0; i < 16; ++i) buf[bo + (size_t)(g * 16 + i) * 64 + d] = acc[i];
  if (tid < 64) {
    float zz = 0.f;
    for (int t = 0; t < 64; ++t) zz += Ks[t][tid];
    buf[bo + 4096 + tid] = zz;
  }
}

// ---------------------------------------------------------------------------
// Pass 2: inclusive scan over 31 chunk states per (b,h)
// ---------------------------------------------------------------------------
__global__ __launch_bounds__(256) void chunk_prefix_kernel(float* __restrict__ buf)
{
  int bh = blockIdx.x / 17;
  int grp = blockIdx.x % 17;
  int e = grp * 256 + threadIdx.x;
  if (e >= CENT_) return;
  size_t base = (size_t)bh * 31 * CENT_ + e;
  float run = 0.f;
  for (int c = 0; c < 31; ++c) {
    run += buf[base + (size_t)c * CENT_];
    buf[base + (size_t)c * CENT_] = run;
  }
}

// ---------------------------------------------------------------------------
// Pass 3: per-chunk attention (pad 65: lane-row reads 2-way, conflict-free)
// ---------------------------------------------------------------------------
__global__ __launch_bounds__(256) void chunk_attn_kernel(
    const float* __restrict__ qf, const float* __restrict__ kf,
    const float* __restrict__ v, const float* __restrict__ buf,
    float* __restrict__ out)
{
  int bh = blockIdx.x >> 5;
  int c  = blockIdx.x & 31;
  int b = bh >> 3, h = bh & 7;
  __shared__ float Qs[64][65], Ks[64][65], Vs[64][65];  // Ks reused for A
  __shared__ float den[64];
  int tid = threadIdx.x;
  int d = tid & 63, g = tid >> 6;
  for (int t4 = 0; t4 < 64; t4 += 4) {
    int t = t4 + g;
    size_t off = ((size_t)(b * T_ + c * 64 + t) * D_) + h * 64 + d;
    Qs[t][d] = qf[off];
    Ks[t][d] = kf[off];
    Vs[t][d] = v[off];
  }
  __syncthreads();
  float a[16];
  {
    int i = d;
#pragma unroll
    for (int jj = 0; jj < 16; ++jj) a[jj] = 0.f;
    for (int m = 0; m < 64; ++m) {
      float qv = Qs[i][m];
#pragma unroll
      for (int jj = 0; jj < 16; ++jj) a[jj] += qv * Ks[g * 16 + jj][m];
    }
  }
  __syncthreads();
  {
    int i = d;
#pragma unroll
    for (int jj = 0; jj < 16; ++jj) {
      int j = g * 16 + jj;
      Ks[i][j] = (j <= i) ? a[jj] : 0.f;
    }
  }
  __syncthreads();
  const float* S0 = buf + (size_t)(bh * 31 + (c - 1)) * CENT_;  // valid if c>0
  if (tid < 64) {
    int i = tid;
    float dn = 0.f;
    for (int j = 0; j < 64; ++j) dn += Ks[i][j];
    if (c > 0) {
      const float* z0 = S0 + 4096;
      for (int m = 0; m < 64; ++m) dn += Qs[i][m] * z0[m];
    }
    den[i] = dn;
  }
  float acc[16];
#pragma unroll
  for (int ii = 0; ii < 16; ++ii) acc[ii] = 0.f;
  for (int j = 0; j < 64; ++j) {
    float vv = Vs[j][d];
#pragma unroll
    for (int ii = 0; ii < 16; ++ii) acc[ii] += Ks[g * 16 + ii][j] * vv;
  }
  if (c > 0) {
    for (int m = 0; m < 64; ++m) {
      float s0 = S0[(size_t)m * 64 + d];
#pragma unroll
      for (int ii = 0; ii < 16; ++ii) acc[ii] += Qs[g * 16 + ii][m] * s0;
    }
  }
  __syncthreads();
#pragma unroll
  for (int ii = 0; ii < 16; ++ii) {
    int i = g * 16 + ii;
    size_t off = ((size_t)(b * T_ + c * 64 + i) * D_) + h * 64 + d;
    out[off] = acc[ii] / (den[i] + 1e-16f);
  }
}

// ---------------------------------------------------------------------------
// x[row,:] += LayerNorm(a[row,:]) * g + b ; also writes bf16 mirror xb
// ---------------------------------------------------------------------------
__global__ __launch_bounds__(256) void ln_add_kernel(
    float* __restrict__ x, bf16* __restrict__ xb, const float* __restrict__ a,
    const float* __restrict__ g, const float* __restrict__ bta)
{
  int row = blockIdx.x;
  int tid = threadIdx.x;
  const float* ar = a + (size_t)row * D_;
  float v0 = ar[tid], v1 = ar[tid + 256];
  __shared__ float red[4];
  float w = v0 + v1;
  for (int o = 32; o > 0; o >>= 1) w += __shfl_down(w, o, 64);
  if ((tid & 63) == 0) red[tid >> 6] = w;
  __syncthreads();
  float mu = (red[0] + red[1] + red[2] + red[3]) * (1.f / 512.f);
  float d0 = v0 - mu, d1 = v1 - mu;
  __syncthreads();
  w = d0 * d0 + d1 * d1;
  for (int o = 32; o > 0; o >>= 1) w += __shfl_down(w, o, 64);
  if ((tid & 63) == 0) red[tid >> 6] = w;
  __syncthreads();
  float var = (red[0] + red[1] + red[2] + red[3]) * (1.f / 512.f);
  float rs = rsqrtf(var + 1e-5f);
  size_t xoff = (size_t)row * D_;
  float n0 = x[xoff + tid]       + d0 * rs * g[tid]       + bta[tid];
  float n1 = x[xoff + tid + 256] + d1 * rs * g[tid + 256] + bta[tid + 256];
  x[xoff + tid]        = n0;
  x[xoff + tid + 256]  = n1;
  xb[xoff + tid]       = __float2bfloat16(n0);
  xb[xoff + tid + 256] = __float2bfloat16(n1);
}

// ---------------------------------------------------------------------------
extern "C" void kernel_launch(void* const* d_in, const int* in_sizes, int n_in,
                              void* d_out, int out_size, void* d_ws, size_t ws_size,
                              hipStream_t stream) {
  const int*   tokens = (const int*)  d_in[0];
  const float* emb    = (const float*)d_in[1];
  const float* Wq     = (const float*)d_in[2];
  const float* bq     = (const float*)d_in[3];
  const float* Wk     = (const float*)d_in[4];
  const float* bk     = (const float*)d_in[5];
  const float* Wv     = (const float*)d_in[6];
  const float* bv     = (const float*)d_in[7];
  const float* rfs    = (const float*)d_in[8];
  const float* ln1g   = (const float*)d_in[9];
  const float* ln1b   = (const float*)d_in[10];
  const float* ln2g   = (const float*)d_in[11];
  const float* ln2b   = (const float*)d_in[12];
  const float* WU     = (const float*)d_in[13];
  const float* bU     = (const float*)d_in[14];
  const float* WV     = (const float*)d_in[15];
  const float* bV     = (const float*)d_in[16];
  const float* Wout   = (const float*)d_in[17];
  const float* bout   = (const float*)d_in[18];
  float* out = (float*)d_out;

  const size_t R = (size_t)BT_ * D_;          // 2,097,152 floats (8 MB)
  float* ws = (float*)d_ws;
  float* x  = ws + 0 * R;
  float* ab = ws + 1 * R;
  float* qb = ws + 2 * R;
  float* kb = ws + 3 * R;
  float* vb = ws + 4 * R;
  float* sb = ws + 5 * R;                     // chunk states (7.9 MB)
  bf16*  xb = (bf16*)(ws + 6 * R);            // R bf16 = 4 MB
  bf16*  hb = (bf16*)qb;                      // FFN hidden bf16 aliases qb+kb
  float* pb = ws + 16 * R;                    // split-K partials (<=32 MB)
  // transposed bf16 weights
  bf16* wT    = (bf16*)(ws + 6 * R + R / 2);
  bf16* WqT   = wT;                            // [L][D][D]  (RF-folded)
  bf16* WkT   = WqT + (size_t)2 * D_ * D_;     // (RF-folded)
  bf16* WvT   = WkT + (size_t)2 * D_ * D_;
  bf16* WUT   = WvT + (size_t)2 * D_ * D_;     // [L][FFN][D]
  bf16* WVT   = WUT + (size_t)2 * D_ * FFN_;   // [L][D][FFN]
  bf16* WoutT = WVT + (size_t)2 * D_ * FFN_;   // [VOCAB][D]
  float* bqf  = (float*)(WoutT + (size_t)VOCAB_ * D_);  // [L][D] folded bias
  float* bkf  = bqf + 2 * D_;

  // ---- weight prep ----
  rf_fold_w_kernel<<<dim3(8, 4, 4), 256, 0, stream>>>(Wq, Wk, rfs, WqT, WkT);
  rf_fold_b_kernel<<<4, 256, 0, stream>>>(bq, bk, rfs, bqf, bkf);
  transpose_cast_kernel<<<dim3(D_/32,  D_/32,  2), 256, 0, stream>>>(Wv,   WvT,   D_,   D_);
  transpose_cast_kernel<<<dim3(FFN_/32,D_/32,  2), 256, 0, stream>>>(WU,   WUT,   D_,   FFN_);
  transpose_cast_kernel<<<dim3(D_/32,  FFN_/32,2), 256, 0, stream>>>(WV,   WVT,   FFN_, D_);
  transpose_cast_kernel<<<dim3(VOCAB_/32, D_/32,1), 256, 0, stream>>>(Wout, WoutT, D_,  VOCAB_);

  embed_pos_kernel<<<BT_, 512, 0, stream>>>(tokens, emb, x, xb);

  for (int l = 0; l < 2; ++l) {
    // batched QKV (q,k RF-folded, favor-exp fused): z = {q,k,v}, 384 blocks
    gemm_qkv<<<dim3(D_/128, BT_/128, 3), 256, 0, stream>>>(
        xb, wT, bqf, bkf, bv, qb, l);

    chunk_sum_kernel<<<16 * 31, 256, 0, stream>>>(kb, vb, sb);
    chunk_prefix_kernel<<<16 * 17, 256, 0, stream>>>(sb);
    chunk_attn_kernel<<<16 * NC_, 256, 0, stream>>>(qb, kb, vb, sb, ab);

    ln_add_kernel<<<BT_, 256, 0, stream>>>(x, xb, ab, ln1g + l*D_, ln1b + l*D_);

    gemm_mfma<<<dim3(FFN_/128, BT_/128), 256, 0, stream>>>(
        xb, WUT + (size_t)l*D_*FFN_, bU + l*FFN_, hb, BT_, FFN_, D_, 1);

    // FFN2 split-K: K=2048 -> 4 x 512, then reduce + bias
    gemm_splitk<<<dim3(D_/128, BT_/128, 4), 256, 0, stream>>>(
        hb, WVT + (size_t)l*FFN_*D_, pb, BT_, D_, FFN_, FFN_/4);
    reduce4_bias_kernel<<<(BT_*D_)/1024, 256, 0, stream>>>(
        pb, bV + l*D_, ab, BT_*D_, D_);

    ln_add_kernel<<<BT_, 256, 0, stream>>>(x, xb, ab, ln2g + l*D_, ln2b + l*D_);
  }

  // Wout split-K: K=512 -> 4 x 128, then reduce + bias
  gemm_splitk<<<dim3(VOCAB_/128, BT_/128, 4), 256, 0, stream>>>(
      xb, WoutT, pb, BT_, VOCAB_, D_, D_/4);
  reduce4_bias_kernel<<<(BT_*VOCAB_)/1024, 256, 0, stream>>>(
      pb, bout, out, BT_*VOCAB_, VOCAB_);
}

// Round 10
// 386.519 us; speedup vs baseline: 1.2302x; 1.0760x over previous
//
#include <hip/hip_runtime.h>
#include <hip/hip_bf16.h>
#include <math.h>

#define B_  2
#define T_  2048
#define D_  512
#define H_  8
#define HD_ 64
#define FFN_ 2048
#define VOCAB_ 256
#define BT_ (B_*T_)
#define NC_ 32            // chunks per (b,h), chunk size 64
#define CENT_ 4160        // floats per chunk state: 64*64 S + 64 z

typedef __attribute__((ext_vector_type(8))) short short8;
typedef __attribute__((ext_vector_type(4))) float float4v;
typedef __hip_bfloat16 bf16;

// async 16B/lane global->LDS DMA (wave-uniform LDS base + lane*16)
__device__ __forceinline__ void load16_lds(const void* g, void* l) {
  __builtin_amdgcn_global_load_lds(
      (const __attribute__((address_space(1))) unsigned int*)g,
      (__attribute__((address_space(3))) unsigned int*)l,
      16, 0, 0);
}

// ---------------------------------------------------------------------------
// Embedding + sinusoidal positional concat; writes fp32 x and bf16 mirror xb
// ---------------------------------------------------------------------------
__global__ __launch_bounds__(512) void embed_pos_kernel(
    const int* __restrict__ tokens, const float* __restrict__ emb,
    float* __restrict__ x, bf16* __restrict__ xb)
{
  int bt = blockIdx.x;          // b*T + t
  int t  = bt & (T_ - 1);
  int j  = threadIdx.x;
  float val;
  if (j < 256) {
    int tok = tokens[bt];
    val = emb[tok * 256 + j];
  } else {
    int jj = (j - 256) & 127;
    float f = expf(-(float)(2 * jj) * (9.210340371976184f / 256.0f));
    float arg = (float)t * f;
    val = (j < 384) ? sinf(arg) : cosf(arg);
  }
  size_t off = (size_t)bt * D_ + j;
  x[off]  = val;
  xb[off] = __float2bfloat16(val);
}

// ---------------------------------------------------------------------------
// All weight transposes (Wv, WU, WV, Wout) + rf_fold_b in ONE launch.
// Flat grid: [0,512) Wv | [512,2560) WU | [2560,4608) WV | [4608,4736) Wout |
// [4736,4740) rf_fold_b.
// ---------------------------------------------------------------------------
__global__ __launch_bounds__(256) void prep_all_kernel(
    const float* __restrict__ Wv, const float* __restrict__ WU,
    const float* __restrict__ WVp, const float* __restrict__ Wout,
    bf16* __restrict__ WvT, bf16* __restrict__ WUT,
    bf16* __restrict__ WVT, bf16* __restrict__ WoutT,
    const float* __restrict__ bq, const float* __restrict__ bk,
    const float* __restrict__ rfs, float* __restrict__ bqf,
    float* __restrict__ bkf)
{
  __shared__ float t[32][33];
  int id = blockIdx.x;
  if (id >= 4736) {                 // rf_fold_b, z = id - 4736
    int z = id - 4736;
    int l = z >> 1, side = z & 1;
    const float* b = (side ? bk : bq) + l * D_;
    float* bo = (side ? bkf : bqf) + l * D_;
    for (int n = threadIdx.x; n < D_; n += 256) {
      int h = n >> 6, j = n & 63;
      const float* R = rfs + ((size_t)l * H_ + h) * 4096;
      float acc = 0.f;
      for (int d = 0; d < 64; ++d) acc += b[h * 64 + d] * R[d * 64 + j];
      bo[n] = acc * 0.35355339059327373f;
    }
    return;
  }
  const float* W; bf16* Wt; int K, N, tx, ty;
  if (id < 512) {                   // Wv: 2 layers x 16x16 tiles
    int l = id >> 8, tt = id & 255;
    W = Wv + (size_t)l * D_ * D_;  Wt = WvT + (size_t)l * D_ * D_;
    K = D_; N = D_; tx = tt & 15; ty = tt >> 4;
  } else if (id < 2560) {           // WU: 2 layers x 64x16 tiles
    int tt = id - 512; int l = tt >> 10; tt &= 1023;
    W = WU + (size_t)l * D_ * FFN_;  Wt = WUT + (size_t)l * D_ * FFN_;
    K = D_; N = FFN_; tx = tt & 63; ty = tt >> 6;
  } else if (id < 4608) {           // WV: 2 layers x 16x64 tiles
    int tt = id - 2560; int l = tt >> 10; tt &= 1023;
    W = WVp + (size_t)l * FFN_ * D_;  Wt = WVT + (size_t)l * FFN_ * D_;
    K = FFN_; N = D_; tx = tt & 15; ty = tt >> 4;
  } else {                          // Wout: 8x16 tiles
    int tt = id - 4608;
    W = Wout;  Wt = WoutT;
    K = D_; N = VOCAB_; tx = tt & 7; ty = tt >> 3;
  }
  int n0 = tx * 32, k0 = ty * 32;
  int lx = threadIdx.x & 31, ly = threadIdx.x >> 5;  // ly 0..7
#pragma unroll
  for (int r = 0; r < 4; ++r)
    t[ly + 8 * r][lx] = W[(size_t)(k0 + ly + 8 * r) * N + n0 + lx];
  __syncthreads();
#pragma unroll
  for (int r = 0; r < 4; ++r)
    Wt[(size_t)(n0 + ly + 8 * r) * K + k0 + lx] = __float2bfloat16(t[lx][ly + 8 * r]);
}

// ---------------------------------------------------------------------------
// RF-fold weights, LDS-staged: W'T[h*64+j, k] = s * sum_d W[k, h*64+d] R_h[d,j]
// grid (h=8, kq=4, z=4), z = l*2+side.
// ---------------------------------------------------------------------------
__global__ __launch_bounds__(256) void rf_fold_w_kernel(
    const float* __restrict__ Wq, const float* __restrict__ Wk,
    const float* __restrict__ rfs, bf16* __restrict__ WqT, bf16* __restrict__ WkT)
{
  int h = blockIdx.x, kq = blockIdx.y, z = blockIdx.z;
  int l = z >> 1, side = z & 1;
  const float* W = (side ? Wk : Wq) + (size_t)l * D_ * D_;
  bf16* WT = (side ? WkT : WqT) + (size_t)l * D_ * D_;
  const float* Rg = rfs + ((size_t)l * H_ + h) * 4096;   // R_h[d][j]
  __shared__ float Rl[64][65];
  __shared__ float Ws[128][65];
  int tid = threadIdx.x;
  for (int i = tid; i < 1024; i += 256) {        // R: 1024 float4
    float4 v4 = ((const float4*)Rg)[i];
    int d = i >> 4, j0 = (i & 15) * 4;
    Rl[d][j0] = v4.x; Rl[d][j0+1] = v4.y; Rl[d][j0+2] = v4.z; Rl[d][j0+3] = v4.w;
  }
  for (int i = tid; i < 2048; i += 256) {        // W: 128 rows x 16 float4
    int r = i >> 4, c0 = (i & 15) * 4;
    float4 v4 = *(const float4*)&W[(size_t)(kq * 128 + r) * D_ + h * 64 + c0];
    Ws[r][c0] = v4.x; Ws[r][c0+1] = v4.y; Ws[r][c0+2] = v4.z; Ws[r][c0+3] = v4.w;
  }
  __syncthreads();
  int lane = tid & 63, w = tid >> 6;             // wave w: j in [16w,16w+16)
  for (int kh = 0; kh < 2; ++kh) {               // k = kh*64 + lane
    int kk = kh * 64 + lane;
#pragma unroll 1
    for (int jj = 0; jj < 16; ++jj) {
      int j = w * 16 + jj;
      float acc = 0.f;
#pragma unroll 16
      for (int d = 0; d < 64; ++d) acc += Ws[kk][d] * Rl[d][j];
      WT[(size_t)(h * 64 + j) * D_ + kq * 128 + kk] =
          __float2bfloat16(acc * 0.35355339059327373f);
    }
  }
}

// ---------------------------------------------------------------------------
// MFMA GEMM core: 128x128 tile, BK=32, global_load_lds staging (m97 loop).
// ---------------------------------------------------------------------------
__device__ __forceinline__ void mfma_core(
    const bf16* __restrict__ A, const bf16* __restrict__ Bt,
    int strideK, int kr, int row0, int col0, float4v acc[4][4])
{
  __shared__ short Al[128 * 32];   // [row][k], k contiguous
  __shared__ short Bl[128 * 32];
  int tid = threadIdx.x;
  int lane = tid & 63, w = tid >> 6;
  int wm = (w >> 1) * 64, wn = (w & 1) * 64;
  int quad = lane >> 4, l16 = lane & 15;

  int r0 = 32 * w + (lane >> 2);
  int ks = (lane & 3) * 8;
  const short* gA0 = (const short*)A + (size_t)(row0 + r0) * strideK + ks;
  const short* gA1 = gA0 + (size_t)16 * strideK;
  const short* gB0 = (const short*)Bt + (size_t)(col0 + r0) * strideK + ks;
  const short* gB1 = gB0 + (size_t)16 * strideK;
  short* lA0 = Al + (32 * w) * 32;
  short* lA1 = Al + (32 * w + 16) * 32;
  short* lB0 = Bl + (32 * w) * 32;
  short* lB1 = Bl + (32 * w + 16) * 32;

  load16_lds(gA0, lA0);
  load16_lds(gA1, lA1);
  load16_lds(gB0, lB0);
  load16_lds(gB1, lB1);

  for (int kt = 0; kt < kr; ++kt) {
    __syncthreads();               // drains vmcnt -> tile kt in LDS
    short8 af[4], bfr[4];
#pragma unroll
    for (int mi = 0; mi < 4; ++mi)
      af[mi] = *(const short8*)&Al[(wm + mi * 16 + l16) * 32 + quad * 8];
#pragma unroll
    for (int ni = 0; ni < 4; ++ni)
      bfr[ni] = *(const short8*)&Bl[(wn + ni * 16 + l16) * 32 + quad * 8];
    __syncthreads();               // frags in regs; LDS reusable
    if (kt + 1 < kr) {             // next-tile DMA overlaps MFMA
      int o = (kt + 1) * 32;
      load16_lds(gA0 + o, lA0);
      load16_lds(gA1 + o, lA1);
      load16_lds(gB0 + o, lB0);
      load16_lds(gB1 + o, lB1);
    }
#pragma unroll
    for (int mi = 0; mi < 4; ++mi)
#pragma unroll
      for (int ni = 0; ni < 4; ++ni)
        acc[mi][ni] = __builtin_amdgcn_mfma_f32_16x16x32_bf16(
            af[mi], bfr[ni], acc[mi][ni], 0, 0, 0);
  }
}

// ---------------------------------------------------------------------------
// Generic GEMM: C = act(A @ Bt^T + bias). mode 0: fp32. mode 1: gelu->bf16.
// ---------------------------------------------------------------------------
__global__ __launch_bounds__(256) void gemm_mfma(
    const bf16* __restrict__ A, const bf16* __restrict__ Bt,
    const float* __restrict__ bias, void* __restrict__ Cout,
    int M, int N, int K, int mode)
{
  int lane = threadIdx.x & 63, w = threadIdx.x >> 6;
  int wm = (w >> 1) * 64, wn = (w & 1) * 64;
  int quad = lane >> 4, l16 = lane & 15;
  int row0 = blockIdx.y * 128, col0 = blockIdx.x * 128;
  float4v acc[4][4] = {};
  mfma_core(A, Bt, K, K >> 5, row0, col0, acc);
#pragma unroll
  for (int mi = 0; mi < 4; ++mi) {
#pragma unroll
    for (int ni = 0; ni < 4; ++ni) {
      int j = col0 + wn + ni * 16 + l16;
      float bj = bias[j];
#pragma unroll
      for (int r = 0; r < 4; ++r) {
        int i = row0 + wm + mi * 16 + quad * 4 + r;
        float v = acc[mi][ni][r] + bj;
        if (mode == 1) {
          v = 0.5f * v * (1.0f + erff(v * 0.7071067811865475f));
          ((bf16*)Cout)[(size_t)i * N + j] = __float2bfloat16(v);
        } else {
          ((float*)Cout)[(size_t)i * N + j] = v;
        }
      }
    }
  }
}

// ---------------------------------------------------------------------------
// Batched QKV GEMM with fused FAVOR exp for q,k: blockIdx.z = {q,k,v}.
// ---------------------------------------------------------------------------
__global__ __launch_bounds__(256) void gemm_qkv(
    const bf16* __restrict__ A, const bf16* __restrict__ wT,
    const float* __restrict__ bqf, const float* __restrict__ bkf,
    const float* __restrict__ bv, float* __restrict__ outb, int l)
{
  int z = blockIdx.z;
  const bf16* Bt = wT + ((size_t)z * 2 + l) * D_ * D_;
  const float* bias = (z == 0 ? bqf : (z == 1 ? bkf : bv)) + l * D_;
  float* Cout = outb + (size_t)z * BT_ * D_;
  int lane = threadIdx.x & 63, w = threadIdx.x >> 6;
  int wm = (w >> 1) * 64, wn = (w & 1) * 64;
  int quad = lane >> 4, l16 = lane & 15;
  int row0 = blockIdx.y * 128, col0 = blockIdx.x * 128;
  float4v acc[4][4] = {};
  mfma_core(A, Bt, D_, D_ >> 5, row0, col0, acc);
  if (z < 2) {
#pragma unroll
    for (int mi = 0; mi < 4; ++mi) {
      float vres[4][4];            // [ni][r]
      float sq[4] = {0.f, 0.f, 0.f, 0.f};
#pragma unroll
      for (int ni = 0; ni < 4; ++ni) {
        int j = col0 + wn + ni * 16 + l16;
        float bj = bias[j];
#pragma unroll
        for (int r = 0; r < 4; ++r) {
          float v = acc[mi][ni][r] + bj;
          vres[ni][r] = v;
          sq[r] += v * v;
        }
      }
#pragma unroll
      for (int r = 0; r < 4; ++r) {
        float s = sq[r];
        s += __shfl_xor(s, 1, 64);
        s += __shfl_xor(s, 2, 64);
        s += __shfl_xor(s, 4, 64);
        s += __shfl_xor(s, 8, 64);
        sq[r] = s;
      }
#pragma unroll
      for (int ni = 0; ni < 4; ++ni) {
        int j = col0 + wn + ni * 16 + l16;
#pragma unroll
        for (int r = 0; r < 4; ++r) {
          int i = row0 + wm + mi * 16 + quad * 4 + r;
          Cout[(size_t)i * D_ + j] = __expf(vres[ni][r] - sq[r] * (1.0f / 128.0f));
        }
      }
    }
  } else {
#pragma unroll
    for (int mi = 0; mi < 4; ++mi) {
#pragma unroll
      for (int ni = 0; ni < 4; ++ni) {
        int j = col0 + wn + ni * 16 + l16;
        float bj = bias[j];
#pragma unroll
        for (int r = 0; r < 4; ++r) {
          int i = row0 + wm + mi * 16 + quad * 4 + r;
          Cout[(size_t)i * D_ + j] = acc[mi][ni][r] + bj;
        }
      }
    }
  }
}

// ---------------------------------------------------------------------------
// Split-K GEMM: P[s][M][N] = A[:, s*KS:(s+1)*KS] @ slice. s = blockIdx.z.
// ---------------------------------------------------------------------------
__global__ __launch_bounds__(256) void gemm_splitk(
    const bf16* __restrict__ A, const bf16* __restrict__ Bt,
    float* __restrict__ P, int M, int N, int K, int KS)
{
  int s = blockIdx.z;
  int lane = threadIdx.x & 63, w = threadIdx.x >> 6;
  int wm = (w >> 1) * 64, wn = (w & 1) * 64;
  int quad = lane >> 4, l16 = lane & 15;
  int row0 = blockIdx.y * 128, col0 = blockIdx.x * 128;
  float4v acc[4][4] = {};
  mfma_core((const bf16*)((const short*)A + s * KS),
            (const bf16*)((const short*)Bt + s * KS),
            K, KS >> 5, row0, col0, acc);
  float* Ps = P + (size_t)s * M * N;
#pragma unroll
  for (int mi = 0; mi < 4; ++mi) {
#pragma unroll
    for (int ni = 0; ni < 4; ++ni) {
      int j = col0 + wn + ni * 16 + l16;
#pragma unroll
      for (int r = 0; r < 4; ++r) {
        int i = row0 + wm + mi * 16 + quad * 4 + r;
        Ps[(size_t)i * N + j] = acc[mi][ni][r];
      }
    }
  }
}

// ---------------------------------------------------------------------------
// Final-output reduce: C = bias + sum of 4 split partials
// ---------------------------------------------------------------------------
__global__ __launch_bounds__(256) void reduce4_bias_kernel(
    const float* __restrict__ P, const float* __restrict__ bias,
    float* __restrict__ C, int MN, int N)
{
  int idx = (blockIdx.x * 256 + threadIdx.x) * 4;
  float4 s0 = *(const float4*)&P[idx];
  float4 s1 = *(const float4*)&P[idx + MN];
  float4 s2 = *(const float4*)&P[idx + 2 * MN];
  float4 s3 = *(const float4*)&P[idx + 3 * MN];
  float4 b  = *(const float4*)&bias[idx & (N - 1)];
  float4 r;
  r.x = s0.x + s1.x + s2.x + s3.x + b.x;
  r.y = s0.y + s1.y + s2.y + s3.y + b.y;
  r.z = s0.z + s1.z + s2.z + s3.z + b.z;
  r.w = s0.w + s1.w + s2.w + s3.w + b.w;
  *(float4*)&C[idx] = r;
}

// ---------------------------------------------------------------------------
// Fused split-K reduce + bias + LayerNorm + residual add (FFN2 epilogue):
// h = sum_s P[s][row] + bias; x += LN(h)*g + b; xb = bf16(x)
// ---------------------------------------------------------------------------
__global__ __launch_bounds__(256) void reduce_ln_add_kernel(
    const float* __restrict__ P, const float* __restrict__ bias,
    float* __restrict__ x, bf16* __restrict__ xb,
    const float* __restrict__ g, const float* __restrict__ bta)
{
  const int MN = BT_ * D_;
  int row = blockIdx.x;
  int tid = threadIdx.x;
  size_t base = (size_t)row * D_;
  float v0 = P[base + tid] + P[MN + base + tid] + P[2 * MN + base + tid]
           + P[3 * MN + base + tid] + bias[tid];
  float v1 = P[base + tid + 256] + P[MN + base + tid + 256]
           + P[2 * MN + base + tid + 256] + P[3 * MN + base + tid + 256]
           + bias[tid + 256];
  __shared__ float red[4];
  float w = v0 + v1;
  for (int o = 32; o > 0; o >>= 1) w += __shfl_down(w, o, 64);
  if ((tid & 63) == 0) red[tid >> 6] = w;
  __syncthreads();
  float mu = (red[0] + red[1] + red[2] + red[3]) * (1.f / 512.f);
  float d0 = v0 - mu, d1 = v1 - mu;
  __syncthreads();
  w = d0 * d0 + d1 * d1;
  for (int o = 32; o > 0; o >>= 1) w += __shfl_down(w, o, 64);
  if ((tid & 63) == 0) red[tid >> 6] = w;
  __syncthreads();
  float var = (red[0] + red[1] + red[2] + red[3]) * (1.f / 512.f);
  float rs = rsqrtf(var + 1e-5f);
  float n0 = x[base + tid]       + d0 * rs * g[tid]       + bta[tid];
  float n1 = x[base + tid + 256] + d1 * rs * g[tid + 256] + bta[tid + 256];
  x[base + tid]        = n0;
  x[base + tid + 256]  = n1;
  xb[base + tid]       = __float2bfloat16(n0);
  xb[base + tid + 256] = __float2bfloat16(n1);
}

// ---------------------------------------------------------------------------
// Pass 1: per-chunk sums (chunks 0..30 per bh). float4 LDS reads, parallel z.
// ---------------------------------------------------------------------------
__global__ __launch_bounds__(256) void chunk_sum_kernel(
    const float* __restrict__ kf, const float* __restrict__ v,
    float* __restrict__ buf)
{
  int bh = blockIdx.x / 31;
  int c  = blockIdx.x % 31;
  int b = bh >> 3, h = bh & 7;
  __shared__ float Ks[64][68], Vs[64][68];
  __shared__ float zpart[4][68];
  int tid = threadIdx.x;
  int d = tid & 63, g = tid >> 6;
  for (int t4 = 0; t4 < 64; t4 += 4) {
    int t = t4 + g;
    size_t off = ((size_t)(b * T_ + c * 64 + t) * D_) + h * 64 + d;
    Ks[t][d] = kf[off];
    Vs[t][d] = v[off];
  }
  __syncthreads();
  float acc[16];
#pragma unroll
  for (int i = 0; i < 16; ++i) acc[i] = 0.f;
  for (int t = 0; t < 64; ++t) {
    float vv = Vs[t][d];
#pragma unroll
    for (int i4 = 0; i4 < 4; ++i4) {
      float4 kv = *(const float4*)&Ks[t][g * 16 + i4 * 4];  // broadcast b128
      acc[i4*4+0] += kv.x * vv;
      acc[i4*4+1] += kv.y * vv;
      acc[i4*4+2] += kv.z * vv;
      acc[i4*4+3] += kv.w * vv;
    }
  }
  float zp = 0.f;
  for (int t = g * 16; t < g * 16 + 16; ++t) zp += Ks[t][d];
  zpart[g][d] = zp;
  size_t bo = (size_t)(bh * 31 + c) * CENT_;
#pragma unroll
  for (int i = 0; i < 16; ++i) buf[bo + (size_t)(g * 16 + i) * 64 + d] = acc[i];
  __syncthreads();
  if (tid < 64)
    buf[bo + 4096 + tid] = zpart[0][tid] + zpart[1][tid] + zpart[2][tid] + zpart[3][tid];
}

// ---------------------------------------------------------------------------
// Pass 2: inclusive scan over 31 chunk states per (b,h)
// ---------------------------------------------------------------------------
__global__ __launch_bounds__(256) void chunk_prefix_kernel(float* __restrict__ buf)
{
  int bh = blockIdx.x / 17;
  int grp = blockIdx.x % 17;
  int e = grp * 256 + threadIdx.x;
  if (e >= CENT_) return;
  size_t base = (size_t)bh * 31 * CENT_ + e;
  float run = 0.f;
  for (int c = 0; c < 31; ++c) {
    run += buf[base + (size_t)c * CENT_];
    buf[base + (size_t)c * CENT_] = run;
  }
}

// ---------------------------------------------------------------------------
// Pass 3: per-chunk attention. Pad 68 (float4-aligned, b128 optimal banking);
// den from mask-phase partials; Qf.z0 parallel over 256 threads.
// ---------------------------------------------------------------------------
__global__ __launch_bounds__(256) void chunk_attn_kernel(
    const float* __restrict__ qf, const float* __restrict__ kf,
    const float* __restrict__ v, const float* __restrict__ buf,
    float* __restrict__ out)
{
  int bh = blockIdx.x >> 5;
  int c  = blockIdx.x & 31;
  int b = bh >> 3, h = bh & 7;
  __shared__ float Qs[64][68], Ks[64][68], Vs[64][68];  // Ks reused for A
  __shared__ float dpart[8][68];
  __shared__ float den[64];
  int tid = threadIdx.x;
  int d = tid & 63, g = tid >> 6;
  for (int t4 = 0; t4 < 64; t4 += 4) {
    int t = t4 + g;
    size_t off = ((size_t)(b * T_ + c * 64 + t) * D_) + h * 64 + d;
    Qs[t][d] = qf[off];
    Ks[t][d] = kf[off];
    Vs[t][d] = v[off];
  }
  __syncthreads();
  // A[i][j] = sum_m Qf[i][m] Kf[j][m]; thread: i = d, j in g's 16-col band
  {
    int i = d;
    float a[16];
#pragma unroll
    for (int jj = 0; jj < 16; ++jj) a[jj] = 0.f;
    for (int m = 0; m < 64; m += 4) {
      float4 qv = *(const float4*)&Qs[i][m];
#pragma unroll
      for (int jj = 0; jj < 16; ++jj) {
        float4 kv = *(const float4*)&Ks[g * 16 + jj][m];  // broadcast b128
        a[jj] += qv.x * kv.x + qv.y * kv.y + qv.z * kv.z + qv.w * kv.w;
      }
    }
    __syncthreads();           // everyone done reading Ks
    float rsum = 0.f;
#pragma unroll
    for (int jj = 0; jj < 16; ++jj) {
      int j = g * 16 + jj;
      a[jj] = (j <= i) ? a[jj] : 0.f;
      rsum += a[jj];
    }
#pragma unroll
    for (int j4 = 0; j4 < 4; ++j4)
      *(float4*)&Ks[i][g * 16 + j4 * 4] =
          make_float4(a[j4*4], a[j4*4+1], a[j4*4+2], a[j4*4+3]);
    dpart[g][i] = rsum;
  }
  // Qf . z0 partials (quarter g covers m in [16g,16g+16))
  const float* S0 = buf + (size_t)(bh * 31 + (c - 1)) * CENT_;  // valid if c>0
  {
    int i = d;
    float qz = 0.f;
    if (c > 0) {
      const float* z0 = S0 + 4096;
      for (int m = g * 16; m < g * 16 + 16; m += 4) {
        float4 qv = *(const float4*)&Qs[i][m];
        qz += qv.x * z0[m] + qv.y * z0[m+1] + qv.z * z0[m+2] + qv.w * z0[m+3];
      }
    }
    dpart[4 + g][i] = qz;
  }
  __syncthreads();
  if (tid < 64)
    den[tid] = dpart[0][tid] + dpart[1][tid] + dpart[2][tid] + dpart[3][tid]
             + dpart[4][tid] + dpart[5][tid] + dpart[6][tid] + dpart[7][tid];
  // num: thread (g,d) owns rows i = g*16..+16, column d. Ks holds masked A.
  float acc[16];
#pragma unroll
  for (int ii = 0; ii < 16; ++ii) acc[ii] = 0.f;
  for (int j = 0; j < 64; j += 4) {
    float va = Vs[j][d], vb2 = Vs[j+1][d], vc = Vs[j+2][d], vd2 = Vs[j+3][d];
#pragma unroll
    for (int ii = 0; ii < 16; ++ii) {
      float4 av = *(const float4*)&Ks[g * 16 + ii][j];    // broadcast b128
      acc[ii] += av.x * va + av.y * vb2 + av.z * vc + av.w * vd2;
    }
  }
  if (c > 0) {
    for (int m = 0; m < 64; m += 4) {
      float sa = S0[(size_t)m * 64 + d];
      float sb2 = S0[(size_t)(m+1) * 64 + d];
      float sc = S0[(size_t)(m+2) * 64 + d];
      float sd2 = S0[(size_t)(m+3) * 64 + d];
#pragma unroll
      for (int ii = 0; ii < 16; ++ii) {
        float4 qv = *(const float4*)&Qs[g * 16 + ii][m];  // broadcast b128
        acc[ii] += qv.x * sa + qv.y * sb2 + qv.z * sc + qv.w * sd2;
      }
    }
  }
  __syncthreads();           // den[] visible
#pragma unroll
  for (int ii = 0; ii < 16; ++ii) {
    int i = g * 16 + ii;
    size_t off = ((size_t)(b * T_ + c * 64 + i) * D_) + h * 64 + d;
    out[off] = acc[ii] / (den[i] + 1e-16f);
  }
}

// ---------------------------------------------------------------------------
// x[row,:] += LayerNorm(a[row,:]) * g + b ; also writes bf16 mirror xb
// ---------------------------------------------------------------------------
__global__ __launch_bounds__(256) void ln_add_kernel(
    float* __restrict__ x, bf16* __restrict__ xb, const float* __restrict__ a,
    const float* __restrict__ g, const float* __restrict__ bta)
{
  int row = blockIdx.x;
  int tid = threadIdx.x;
  const float* ar = a + (size_t)row * D_;
  float v0 = ar[tid], v1 = ar[tid + 256];
  __shared__ float red[4];
  float w = v0 + v1;
  for (int o = 32; o > 0; o >>= 1) w += __shfl_down(w, o, 64);
  if ((tid & 63) == 0) red[tid >> 6] = w;
  __syncthreads();
  float mu = (red[0] + red[1] + red[2] + red[3]) * (1.f / 512.f);
  float d0 = v0 - mu, d1 = v1 - mu;
  __syncthreads();
  w = d0 * d0 + d1 * d1;
  for (int o = 32; o > 0; o >>= 1) w += __shfl_down(w, o, 64);
  if ((tid & 63) == 0) red[tid >> 6] = w;
  __syncthreads();
  float var = (red[0] + red[1] + red[2] + red[3]) * (1.f / 512.f);
  float rs = rsqrtf(var + 1e-5f);
  size_t xoff = (size_t)row * D_;
  float n0 = x[xoff + tid]       + d0 * rs * g[tid]       + bta[tid];
  float n1 = x[xoff + tid + 256] + d1 * rs * g[tid + 256] + bta[tid + 256];
  x[xoff + tid]        = n0;
  x[xoff + tid + 256]  = n1;
  xb[xoff + tid]       = __float2bfloat16(n0);
  xb[xoff + tid + 256] = __float2bfloat16(n1);
}

// ---------------------------------------------------------------------------
extern "C" void kernel_launch(void* const* d_in, const int* in_sizes, int n_in,
                              void* d_out, int out_size, void* d_ws, size_t ws_size,
                              hipStream_t stream) {
  const int*   tokens = (const int*)  d_in[0];
  const float* emb    = (const float*)d_in[1];
  const float* Wq     = (const float*)d_in[2];
  const float* bq     = (const float*)d_in[3];
  const float* Wk     = (const float*)d_in[4];
  const float* bk     = (const float*)d_in[5];
  const float* Wv     = (const float*)d_in[6];
  const float* bv     = (const float*)d_in[7];
  const float* rfs    = (const float*)d_in[8];
  const float* ln1g   = (const float*)d_in[9];
  const float* ln1b   = (const float*)d_in[10];
  const float* ln2g   = (const float*)d_in[11];
  const float* ln2b   = (const float*)d_in[12];
  const float* WU     = (const float*)d_in[13];
  const float* bU     = (const float*)d_in[14];
  const float* WV     = (const float*)d_in[15];
  const float* bV     = (const float*)d_in[16];
  const float* Wout   = (const float*)d_in[17];
  const float* bout   = (const float*)d_in[18];
  float* out = (float*)d_out;

  const size_t R = (size_t)BT_ * D_;          // 2,097,152 floats (8 MB)
  float* ws = (float*)d_ws;
  float* x  = ws + 0 * R;
  float* ab = ws + 1 * R;
  float* qb = ws + 2 * R;
  float* kb = ws + 3 * R;
  float* vb = ws + 4 * R;
  float* sb = ws + 5 * R;                     // chunk states (7.9 MB)
  bf16*  xb = (bf16*)(ws + 6 * R);            // R bf16 = 4 MB
  bf16*  hb = (bf16*)qb;                      // FFN hidden bf16 aliases qb+kb
  float* pb = ws + 16 * R;                    // split-K partials (<=32 MB)
  // transposed bf16 weights
  bf16* wT    = (bf16*)(ws + 6 * R + R / 2);
  bf16* WqT   = wT;                            // [L][D][D]  (RF-folded)
  bf16* WkT   = WqT + (size_t)2 * D_ * D_;     // (RF-folded)
  bf16* WvT   = WkT + (size_t)2 * D_ * D_;
  bf16* WUT   = WvT + (size_t)2 * D_ * D_;     // [L][FFN][D]
  bf16* WVT   = WUT + (size_t)2 * D_ * FFN_;   // [L][D][FFN]
  bf16* WoutT = WVT + (size_t)2 * D_ * FFN_;   // [VOCAB][D]
  float* bqf  = (float*)(WoutT + (size_t)VOCAB_ * D_);  // [L][D] folded bias
  float* bkf  = bqf + 2 * D_;

  // ---- weight prep: 2 launches ----
  rf_fold_w_kernel<<<dim3(8, 4, 4), 256, 0, stream>>>(Wq, Wk, rfs, WqT, WkT);
  prep_all_kernel<<<4740, 256, 0, stream>>>(
      Wv, WU, WV, Wout, WvT, WUT, WVT, WoutT, bq, bk, rfs, bqf, bkf);

  embed_pos_kernel<<<BT_, 512, 0, stream>>>(tokens, emb, x, xb);

  for (int l = 0; l < 2; ++l) {
    // batched QKV (q,k RF-folded, favor-exp fused): z = {q,k,v}, 384 blocks
    gemm_qkv<<<dim3(D_/128, BT_/128, 3), 256, 0, stream>>>(
        xb, wT, bqf, bkf, bv, qb, l);

    chunk_sum_kernel<<<16 * 31, 256, 0, stream>>>(kb, vb, sb);
    chunk_prefix_kernel<<<16 * 17, 256, 0, stream>>>(sb);
    chunk_attn_kernel<<<16 * NC_, 256, 0, stream>>>(qb, kb, vb, sb, ab);

    ln_add_kernel<<<BT_, 256, 0, stream>>>(x, xb, ab, ln1g + l*D_, ln1b + l*D_);

    gemm_mfma<<<dim3(FFN_/128, BT_/128), 256, 0, stream>>>(
        xb, WUT + (size_t)l*D_*FFN_, bU + l*FFN_, hb, BT_, FFN_, D_, 1);

    // FFN2 split-K: K=2048 -> 4 x 512, then fused reduce+bias+LN+residual
    gemm_splitk<<<dim3(D_/128, BT_/128, 4), 256, 0, stream>>>(
        hb, WVT + (size_t)l*FFN_*D_, pb, BT_, D_, FFN_, FFN_/4);
    reduce_ln_add_kernel<<<BT_, 256, 0, stream>>>(
        pb, bV + l*D_, x, xb, ln2g + l*D_, ln2b + l*D_);
  }

  // Wout split-K: K=512 -> 4 x 128, then reduce + bias
  gemm_splitk<<<dim3(VOCAB_/128, BT_/128, 4), 256, 0, stream>>>(
      xb, WoutT, pb, BT_, VOCAB_, D_, D_/4);
  reduce4_bias_kernel<<<(BT_*VOCAB_)/1024, 256, 0, stream>>>(
      pb, bout, out, BT_*VOCAB_, VOCAB_);
}

// Round 11
// 372.605 us; speedup vs baseline: 1.2761x; 1.0373x over previous
//
#include <hip/hip_runtime.h>
#include <hip/hip_bf16.h>
#include <math.h>

#define B_  2
#define T_  2048
#define D_  512
#define H_  8
#define HD_ 64
#define FFN_ 2048
#define VOCAB_ 256
#define BT_ (B_*T_)
#define NC_ 32            // chunks per (b,h), chunk size 64
#define CENT_ 4160        // floats per chunk state: 64*64 S + 64 z

typedef __attribute__((ext_vector_type(8))) short short8;
typedef __attribute__((ext_vector_type(4))) float float4v;
typedef __hip_bfloat16 bf16;

// async 16B/lane global->LDS DMA (wave-uniform LDS base + lane*16)
__device__ __forceinline__ void load16_lds(const void* g, void* l) {
  __builtin_amdgcn_global_load_lds(
      (const __attribute__((address_space(1))) unsigned int*)g,
      (__attribute__((address_space(3))) unsigned int*)l,
      16, 0, 0);
}

// ---------------------------------------------------------------------------
// Embedding + sinusoidal positional concat; writes fp32 x and bf16 mirror xb
// ---------------------------------------------------------------------------
__global__ __launch_bounds__(512) void embed_pos_kernel(
    const int* __restrict__ tokens, const float* __restrict__ emb,
    float* __restrict__ x, bf16* __restrict__ xb)
{
  int bt = blockIdx.x;          // b*T + t
  int t  = bt & (T_ - 1);
  int j  = threadIdx.x;
  float val;
  if (j < 256) {
    int tok = tokens[bt];
    val = emb[tok * 256 + j];
  } else {
    int jj = (j - 256) & 127;
    float f = expf(-(float)(2 * jj) * (9.210340371976184f / 256.0f));
    float arg = (float)t * f;
    val = (j < 384) ? sinf(arg) : cosf(arg);
  }
  size_t off = (size_t)bt * D_ + j;
  x[off]  = val;
  xb[off] = __float2bfloat16(val);
}

// ---------------------------------------------------------------------------
// All weight transposes (Wv, WU, WV, Wout) + rf_fold_b in ONE launch.
// Flat grid: [0,512) Wv | [512,2560) WU | [2560,4608) WV | [4608,4736) Wout |
// [4736,4740) rf_fold_b.
// ---------------------------------------------------------------------------
__global__ __launch_bounds__(256) void prep_all_kernel(
    const float* __restrict__ Wv, const float* __restrict__ WU,
    const float* __restrict__ WVp, const float* __restrict__ Wout,
    bf16* __restrict__ WvT, bf16* __restrict__ WUT,
    bf16* __restrict__ WVT, bf16* __restrict__ WoutT,
    const float* __restrict__ bq, const float* __restrict__ bk,
    const float* __restrict__ rfs, float* __restrict__ bqf,
    float* __restrict__ bkf)
{
  __shared__ float t[32][33];
  int id = blockIdx.x;
  if (id >= 4736) {                 // rf_fold_b, z = id - 4736
    int z = id - 4736;
    int l = z >> 1, side = z & 1;
    const float* b = (side ? bk : bq) + l * D_;
    float* bo = (side ? bkf : bqf) + l * D_;
    for (int n = threadIdx.x; n < D_; n += 256) {
      int h = n >> 6, j = n & 63;
      const float* R = rfs + ((size_t)l * H_ + h) * 4096;
      float acc = 0.f;
      for (int d = 0; d < 64; ++d) acc += b[h * 64 + d] * R[d * 64 + j];
      bo[n] = acc * 0.35355339059327373f;
    }
    return;
  }
  const float* W; bf16* Wt; int K, N, tx, ty;
  if (id < 512) {                   // Wv: 2 layers x 16x16 tiles
    int l = id >> 8, tt = id & 255;
    W = Wv + (size_t)l * D_ * D_;  Wt = WvT + (size_t)l * D_ * D_;
    K = D_; N = D_; tx = tt & 15; ty = tt >> 4;
  } else if (id < 2560) {           // WU: 2 layers x 64x16 tiles
    int tt = id - 512; int l = tt >> 10; tt &= 1023;
    W = WU + (size_t)l * D_ * FFN_;  Wt = WUT + (size_t)l * D_ * FFN_;
    K = D_; N = FFN_; tx = tt & 63; ty = tt >> 6;
  } else if (id < 4608) {           // WV: 2 layers x 16x64 tiles
    int tt = id - 2560; int l = tt >> 10; tt &= 1023;
    W = WVp + (size_t)l * FFN_ * D_;  Wt = WVT + (size_t)l * FFN_ * D_;
    K = FFN_; N = D_; tx = tt & 15; ty = tt >> 4;
  } else {                          // Wout: 8x16 tiles
    int tt = id - 4608;
    W = Wout;  Wt = WoutT;
    K = D_; N = VOCAB_; tx = tt & 7; ty = tt >> 3;
  }
  int n0 = tx * 32, k0 = ty * 32;
  int lx = threadIdx.x & 31, ly = threadIdx.x >> 5;  // ly 0..7
#pragma unroll
  for (int r = 0; r < 4; ++r)
    t[ly + 8 * r][lx] = W[(size_t)(k0 + ly + 8 * r) * N + n0 + lx];
  __syncthreads();
#pragma unroll
  for (int r = 0; r < 4; ++r)
    Wt[(size_t)(n0 + ly + 8 * r) * K + k0 + lx] = __float2bfloat16(t[lx][ly + 8 * r]);
}

// ---------------------------------------------------------------------------
// RF-fold weights, LDS-staged: W'T[h*64+j, k] = s * sum_d W[k, h*64+d] R_h[d,j]
// grid (h=8, kq=4, z=4), z = l*2+side.
// ---------------------------------------------------------------------------
__global__ __launch_bounds__(256) void rf_fold_w_kernel(
    const float* __restrict__ Wq, const float* __restrict__ Wk,
    const float* __restrict__ rfs, bf16* __restrict__ WqT, bf16* __restrict__ WkT)
{
  int h = blockIdx.x, kq = blockIdx.y, z = blockIdx.z;
  int l = z >> 1, side = z & 1;
  const float* W = (side ? Wk : Wq) + (size_t)l * D_ * D_;
  bf16* WT = (side ? WkT : WqT) + (size_t)l * D_ * D_;
  const float* Rg = rfs + ((size_t)l * H_ + h) * 4096;   // R_h[d][j]
  __shared__ float Rl[64][65];
  __shared__ float Ws[128][65];
  int tid = threadIdx.x;
  for (int i = tid; i < 1024; i += 256) {        // R: 1024 float4
    float4 v4 = ((const float4*)Rg)[i];
    int d = i >> 4, j0 = (i & 15) * 4;
    Rl[d][j0] = v4.x; Rl[d][j0+1] = v4.y; Rl[d][j0+2] = v4.z; Rl[d][j0+3] = v4.w;
  }
  for (int i = tid; i < 2048; i += 256) {        // W: 128 rows x 16 float4
    int r = i >> 4, c0 = (i & 15) * 4;
    float4 v4 = *(const float4*)&W[(size_t)(kq * 128 + r) * D_ + h * 64 + c0];
    Ws[r][c0] = v4.x; Ws[r][c0+1] = v4.y; Ws[r][c0+2] = v4.z; Ws[r][c0+3] = v4.w;
  }
  __syncthreads();
  int lane = tid & 63, w = tid >> 6;             // wave w: j in [16w,16w+16)
  for (int kh = 0; kh < 2; ++kh) {               // k = kh*64 + lane
    int kk = kh * 64 + lane;
#pragma unroll 1
    for (int jj = 0; jj < 16; ++jj) {
      int j = w * 16 + jj;
      float acc = 0.f;
#pragma unroll 16
      for (int d = 0; d < 64; ++d) acc += Ws[kk][d] * Rl[d][j];
      WT[(size_t)(h * 64 + j) * D_ + kq * 128 + kk] =
          __float2bfloat16(acc * 0.35355339059327373f);
    }
  }
}

// ---------------------------------------------------------------------------
// MFMA GEMM core: 128x128 tile, BK=64, global_load_lds staging (m97 loop,
// half the barriers of BK=32). LDS rows of 64 shorts (8 chunks of 16B) with
// XOR chunk swizzle: slot s of row r holds global chunk s^(r&7). Frag b128
// reads then land 8 dwords/bank (optimal); DMA stays lane-contiguous since
// we permute which global chunk each lane FETCHES, not where it lands.
// kr = K/64 iterations.
// ---------------------------------------------------------------------------
__device__ __forceinline__ void mfma_core(
    const bf16* __restrict__ A, const bf16* __restrict__ Bt,
    int strideK, int kr, int row0, int col0, float4v acc[4][4])
{
  __shared__ short Al[128 * 64];   // [row][64k], swizzled chunks (16 KB)
  __shared__ short Bl[128 * 64];
  int tid = threadIdx.x;
  int lane = tid & 63, w = tid >> 6;
  int wm = (w >> 1) * 64, wn = (w & 1) * 64;
  int quad = lane >> 4, l16 = lane & 15;

  // DMA: wave w stages A and B rows [32w, 32w+32) as 4 segs of 8 rows.
  // Lane l -> seg row (l>>3), LDS slot (l&7); fetches global chunk (l&7)^(l>>3).
  int lr = lane >> 3;                   // 0..7
  int ks = (((lane & 7) ^ lr)) * 8;     // swizzled global chunk, short offset
  const short* gA[4]; const short* gB[4];
  short* lA[4]; short* lB[4];
#pragma unroll
  for (int p = 0; p < 4; ++p) {
    int r = 32 * w + 8 * p;
    gA[p] = (const short*)A + (size_t)(row0 + r + lr) * strideK + ks;
    gB[p] = (const short*)Bt + (size_t)(col0 + r + lr) * strideK + ks;
    lA[p] = Al + r * 64;
    lB[p] = Bl + r * 64;
  }
#pragma unroll
  for (int p = 0; p < 4; ++p) {
    load16_lds(gA[p], lA[p]);
    load16_lds(gB[p], lB[p]);
  }

  for (int kt = 0; kt < kr; ++kt) {
    __syncthreads();               // drains vmcnt -> tile kt in LDS
    short8 af[4][2], bfr[4][2];
#pragma unroll
    for (int mi = 0; mi < 4; ++mi) {
      int R = wm + mi * 16 + l16;
#pragma unroll
      for (int s = 0; s < 2; ++s) {
        int slot = (s * 4 + quad) ^ (R & 7);
        af[mi][s] = *(const short8*)&Al[R * 64 + slot * 8];
      }
    }
#pragma unroll
    for (int ni = 0; ni < 4; ++ni) {
      int R = wn + ni * 16 + l16;
#pragma unroll
      for (int s = 0; s < 2; ++s) {
        int slot = (s * 4 + quad) ^ (R & 7);
        bfr[ni][s] = *(const short8*)&Bl[R * 64 + slot * 8];
      }
    }
    __syncthreads();               // frags in regs; LDS reusable
    if (kt + 1 < kr) {             // next-tile DMA overlaps MFMA
      int o = (kt + 1) * 64;
#pragma unroll
      for (int p = 0; p < 4; ++p) {
        load16_lds(gA[p] + o, lA[p]);
        load16_lds(gB[p] + o, lB[p]);
      }
    }
#pragma unroll
    for (int mi = 0; mi < 4; ++mi)
#pragma unroll
      for (int ni = 0; ni < 4; ++ni) {
        acc[mi][ni] = __builtin_amdgcn_mfma_f32_16x16x32_bf16(
            af[mi][0], bfr[ni][0], acc[mi][ni], 0, 0, 0);
        acc[mi][ni] = __builtin_amdgcn_mfma_f32_16x16x32_bf16(
            af[mi][1], bfr[ni][1], acc[mi][ni], 0, 0, 0);
      }
  }
}

// ---------------------------------------------------------------------------
// Generic GEMM: C = act(A @ Bt^T + bias). mode 0: fp32. mode 1: gelu->bf16.
// ---------------------------------------------------------------------------
__global__ __launch_bounds__(256) void gemm_mfma(
    const bf16* __restrict__ A, const bf16* __restrict__ Bt,
    const float* __restrict__ bias, void* __restrict__ Cout,
    int M, int N, int K, int mode)
{
  int lane = threadIdx.x & 63, w = threadIdx.x >> 6;
  int wm = (w >> 1) * 64, wn = (w & 1) * 64;
  int quad = lane >> 4, l16 = lane & 15;
  int row0 = blockIdx.y * 128, col0 = blockIdx.x * 128;
  float4v acc[4][4] = {};
  mfma_core(A, Bt, K, K >> 6, row0, col0, acc);
#pragma unroll
  for (int mi = 0; mi < 4; ++mi) {
#pragma unroll
    for (int ni = 0; ni < 4; ++ni) {
      int j = col0 + wn + ni * 16 + l16;
      float bj = bias[j];
#pragma unroll
      for (int r = 0; r < 4; ++r) {
        int i = row0 + wm + mi * 16 + quad * 4 + r;
        float v = acc[mi][ni][r] + bj;
        if (mode == 1) {
          v = 0.5f * v * (1.0f + erff(v * 0.7071067811865475f));
          ((bf16*)Cout)[(size_t)i * N + j] = __float2bfloat16(v);
        } else {
          ((float*)Cout)[(size_t)i * N + j] = v;
        }
      }
    }
  }
}

// ---------------------------------------------------------------------------
// Batched QKV GEMM with fused FAVOR exp for q,k: blockIdx.z = {q,k,v}.
// ---------------------------------------------------------------------------
__global__ __launch_bounds__(256) void gemm_qkv(
    const bf16* __restrict__ A, const bf16* __restrict__ wT,
    const float* __restrict__ bqf, const float* __restrict__ bkf,
    const float* __restrict__ bv, float* __restrict__ outb, int l)
{
  int z = blockIdx.z;
  const bf16* Bt = wT + ((size_t)z * 2 + l) * D_ * D_;
  const float* bias = (z == 0 ? bqf : (z == 1 ? bkf : bv)) + l * D_;
  float* Cout = outb + (size_t)z * BT_ * D_;
  int lane = threadIdx.x & 63, w = threadIdx.x >> 6;
  int wm = (w >> 1) * 64, wn = (w & 1) * 64;
  int quad = lane >> 4, l16 = lane & 15;
  int row0 = blockIdx.y * 128, col0 = blockIdx.x * 128;
  float4v acc[4][4] = {};
  mfma_core(A, Bt, D_, D_ >> 6, row0, col0, acc);
  if (z < 2) {
#pragma unroll
    for (int mi = 0; mi < 4; ++mi) {
      float vres[4][4];            // [ni][r]
      float sq[4] = {0.f, 0.f, 0.f, 0.f};
#pragma unroll
      for (int ni = 0; ni < 4; ++ni) {
        int j = col0 + wn + ni * 16 + l16;
        float bj = bias[j];
#pragma unroll
        for (int r = 0; r < 4; ++r) {
          float v = acc[mi][ni][r] + bj;
          vres[ni][r] = v;
          sq[r] += v * v;
        }
      }
#pragma unroll
      for (int r = 0; r < 4; ++r) {
        float s = sq[r];
        s += __shfl_xor(s, 1, 64);
        s += __shfl_xor(s, 2, 64);
        s += __shfl_xor(s, 4, 64);
        s += __shfl_xor(s, 8, 64);
        sq[r] = s;
      }
#pragma unroll
      for (int ni = 0; ni < 4; ++ni) {
        int j = col0 + wn + ni * 16 + l16;
#pragma unroll
        for (int r = 0; r < 4; ++r) {
          int i = row0 + wm + mi * 16 + quad * 4 + r;
          Cout[(size_t)i * D_ + j] = __expf(vres[ni][r] - sq[r] * (1.0f / 128.0f));
        }
      }
    }
  } else {
#pragma unroll
    for (int mi = 0; mi < 4; ++mi) {
#pragma unroll
      for (int ni = 0; ni < 4; ++ni) {
        int j = col0 + wn + ni * 16 + l16;
        float bj = bias[j];
#pragma unroll
        for (int r = 0; r < 4; ++r) {
          int i = row0 + wm + mi * 16 + quad * 4 + r;
          Cout[(size_t)i * D_ + j] = acc[mi][ni][r] + bj;
        }
      }
    }
  }
}

// ---------------------------------------------------------------------------
// Split-K GEMM: P[s][M][N] = A[:, s*KS:(s+1)*KS] @ slice. s = blockIdx.z.
// ---------------------------------------------------------------------------
__global__ __launch_bounds__(256) void gemm_splitk(
    const bf16* __restrict__ A, const bf16* __restrict__ Bt,
    float* __restrict__ P, int M, int N, int K, int KS)
{
  int s = blockIdx.z;
  int lane = threadIdx.x & 63, w = threadIdx.x >> 6;
  int wm = (w >> 1) * 64, wn = (w & 1) * 64;
  int quad = lane >> 4, l16 = lane & 15;
  int row0 = blockIdx.y * 128, col0 = blockIdx.x * 128;
  float4v acc[4][4] = {};
  mfma_core((const bf16*)((const short*)A + s * KS),
            (const bf16*)((const short*)Bt + s * KS),
            K, KS >> 6, row0, col0, acc);
  float* Ps = P + (size_t)s * M * N;
#pragma unroll
  for (int mi = 0; mi < 4; ++mi) {
#pragma unroll
    for (int ni = 0; ni < 4; ++ni) {
      int j = col0 + wn + ni * 16 + l16;
#pragma unroll
      for (int r = 0; r < 4; ++r) {
        int i = row0 + wm + mi * 16 + quad * 4 + r;
        Ps[(size_t)i * N + j] = acc[mi][ni][r];
      }
    }
  }
}

// ---------------------------------------------------------------------------
// Final-output reduce: C = bias + sum of 4 split partials
// ---------------------------------------------------------------------------
__global__ __launch_bounds__(256) void reduce4_bias_kernel(
    const float* __restrict__ P, const float* __restrict__ bias,
    float* __restrict__ C, int MN, int N)
{
  int idx = (blockIdx.x * 256 + threadIdx.x) * 4;
  float4 s0 = *(const float4*)&P[idx];
  float4 s1 = *(const float4*)&P[idx + MN];
  float4 s2 = *(const float4*)&P[idx + 2 * MN];
  float4 s3 = *(const float4*)&P[idx + 3 * MN];
  float4 b  = *(const float4*)&bias[idx & (N - 1)];
  float4 r;
  r.x = s0.x + s1.x + s2.x + s3.x + b.x;
  r.y = s0.y + s1.y + s2.y + s3.y + b.y;
  r.z = s0.z + s1.z + s2.z + s3.z + b.z;
  r.w = s0.w + s1.w + s2.w + s3.w + b.w;
  *(float4*)&C[idx] = r;
}

// ---------------------------------------------------------------------------
// Fused split-K reduce + bias + LayerNorm + residual add (FFN2 epilogue):
// h = sum_s P[s][row] + bias; x += LN(h)*g + b; xb = bf16(x)
// ---------------------------------------------------------------------------
__global__ __launch_bounds__(256) void reduce_ln_add_kernel(
    const float* __restrict__ P, const float* __restrict__ bias,
    float* __restrict__ x, bf16* __restrict__ xb,
    const float* __restrict__ g, const float* __restrict__ bta)
{
  const int MN = BT_ * D_;
  int row = blockIdx.x;
  int tid = threadIdx.x;
  size_t base = (size_t)row * D_;
  float v0 = P[base + tid] + P[MN + base + tid] + P[2 * MN + base + tid]
           + P[3 * MN + base + tid] + bias[tid];
  float v1 = P[base + tid + 256] + P[MN + base + tid + 256]
           + P[2 * MN + base + tid + 256] + P[3 * MN + base + tid + 256]
           + bias[tid + 256];
  __shared__ float red[4];
  float w = v0 + v1;
  for (int o = 32; o > 0; o >>= 1) w += __shfl_down(w, o, 64);
  if ((tid & 63) == 0) red[tid >> 6] = w;
  __syncthreads();
  float mu = (red[0] + red[1] + red[2] + red[3]) * (1.f / 512.f);
  float d0 = v0 - mu, d1 = v1 - mu;
  __syncthreads();
  w = d0 * d0 + d1 * d1;
  for (int o = 32; o > 0; o >>= 1) w += __shfl_down(w, o, 64);
  if ((tid & 63) == 0) red[tid >> 6] = w;
  __syncthreads();
  float var = (red[0] + red[1] + red[2] + red[3]) * (1.f / 512.f);
  float rs = rsqrtf(var + 1e-5f);
  float n0 = x[base + tid]       + d0 * rs * g[tid]       + bta[tid];
  float n1 = x[base + tid + 256] + d1 * rs * g[tid + 256] + bta[tid + 256];
  x[base + tid]        = n0;
  x[base + tid + 256]  = n1;
  xb[base + tid]       = __float2bfloat16(n0);
  xb[base + tid + 256] = __float2bfloat16(n1);
}

// ---------------------------------------------------------------------------
// Pass 1: per-chunk sums (chunks 0..30 per bh). float4 LDS reads, parallel z.
// ---------------------------------------------------------------------------
__global__ __launch_bounds__(256) void chunk_sum_kernel(
    const float* __restrict__ kf, const float* __restrict__ v,
    float* __restrict__ buf)
{
  int bh = blockIdx.x / 31;
  int c  = blockIdx.x % 31;
  int b = bh >> 3, h = bh & 7;
  __shared__ float Ks[64][68], Vs[64][68];
  __shared__ float zpart[4][68];
  int tid = threadIdx.x;
  int d = tid & 63, g = tid >> 6;
  for (int t4 = 0; t4 < 64; t4 += 4) {
    int t = t4 + g;
    size_t off = ((size_t)(b * T_ + c * 64 + t) * D_) + h * 64 + d;
    Ks[t][d] = kf[off];
    Vs[t][d] = v[off];
  }
  __syncthreads();
  float acc[16];
#pragma unroll
  for (int i = 0; i < 16; ++i) acc[i] = 0.f;
  for (int t = 0; t < 64; ++t) {
    float vv = Vs[t][d];
#pragma unroll
    for (int i4 = 0; i4 < 4; ++i4) {
      float4 kv = *(const float4*)&Ks[t][g * 16 + i4 * 4];  // broadcast b128
      acc[i4*4+0] += kv.x * vv;
      acc[i4*4+1] += kv.y * vv;
      acc[i4*4+2] += kv.z * vv;
      acc[i4*4+3] += kv.w * vv;
    }
  }
  float zp = 0.f;
  for (int t = g * 16; t < g * 16 + 16; ++t) zp += Ks[t][d];
  zpart[g][d] = zp;
  size_t bo = (size_t)(bh * 31 + c) * CENT_;
#pragma unroll
  for (int i = 0; i < 16; ++i) buf[bo + (size_t)(g * 16 + i) * 64 + d] = acc[i];
  __syncthreads();
  if (tid < 64)
    buf[bo + 4096 + tid] = zpart[0][tid] + zpart[1][tid] + zpart[2][tid] + zpart[3][tid];
}

// ---------------------------------------------------------------------------
// Pass 2: inclusive scan over 31 chunk states per (b,h).
// Load all 31 first (31 outstanding loads), then scan + store.
// ---------------------------------------------------------------------------
__global__ __launch_bounds__(256) void chunk_prefix_kernel(float* __restrict__ buf)
{
  int bh = blockIdx.x / 17;
  int grp = blockIdx.x % 17;
  int e = grp * 256 + threadIdx.x;
  if (e >= CENT_) return;
  size_t base = (size_t)bh * 31 * CENT_ + e;
  float vals[31];
#pragma unroll
  for (int c = 0; c < 31; ++c) vals[c] = buf[base + (size_t)c * CENT_];
  float run = 0.f;
#pragma unroll
  for (int c = 0; c < 31; ++c) {
    run += vals[c];
    buf[base + (size_t)c * CENT_] = run;
  }
}

// ---------------------------------------------------------------------------
// Pass 3: per-chunk attention. Pad 68 (float4-aligned, b128 optimal banking);
// den from mask-phase partials; Qf.z0 parallel over 256 threads.
// ---------------------------------------------------------------------------
__global__ __launch_bounds__(256) void chunk_attn_kernel(
    const float* __restrict__ qf, const float* __restrict__ kf,
    const float* __restrict__ v, const float* __restrict__ buf,
    float* __restrict__ out)
{
  int bh = blockIdx.x >> 5;
  int c  = blockIdx.x & 31;
  int b = bh >> 3, h = bh & 7;
  __shared__ float Qs[64][68], Ks[64][68], Vs[64][68];  // Ks reused for A
  __shared__ float dpart[8][68];
  __shared__ float den[64];
  int tid = threadIdx.x;
  int d = tid & 63, g = tid >> 6;
  for (int t4 = 0; t4 < 64; t4 += 4) {
    int t = t4 + g;
    size_t off = ((size_t)(b * T_ + c * 64 + t) * D_) + h * 64 + d;
    Qs[t][d] = qf[off];
    Ks[t][d] = kf[off];
    Vs[t][d] = v[off];
  }
  __syncthreads();
  // A[i][j] = sum_m Qf[i][m] Kf[j][m]; thread: i = d, j in g's 16-col band
  {
    int i = d;
    float a[16];
#pragma unroll
    for (int jj = 0; jj < 16; ++jj) a[jj] = 0.f;
    for (int m = 0; m < 64; m += 4) {
      float4 qv = *(const float4*)&Qs[i][m];
#pragma unroll
      for (int jj = 0; jj < 16; ++jj) {
        float4 kv = *(const float4*)&Ks[g * 16 + jj][m];  // broadcast b128
        a[jj] += qv.x * kv.x + qv.y * kv.y + qv.z * kv.z + qv.w * kv.w;
      }
    }
    __syncthreads();           // everyone done reading Ks
    float rsum = 0.f;
#pragma unroll
    for (int jj = 0; jj < 16; ++jj) {
      int j = g * 16 + jj;
      a[jj] = (j <= i) ? a[jj] : 0.f;
      rsum += a[jj];
    }
#pragma unroll
    for (int j4 = 0; j4 < 4; ++j4)
      *(float4*)&Ks[i][g * 16 + j4 * 4] =
          make_float4(a[j4*4], a[j4*4+1], a[j4*4+2], a[j4*4+3]);
    dpart[g][i] = rsum;
  }
  // Qf . z0 partials (quarter g covers m in [16g,16g+16))
  const float* S0 = buf + (size_t)(bh * 31 + (c - 1)) * CENT_;  // valid if c>0
  {
    int i = d;
    float qz = 0.f;
    if (c > 0) {
      const float* z0 = S0 + 4096;
      for (int m = g * 16; m < g * 16 + 16; m += 4) {
        float4 qv = *(const float4*)&Qs[i][m];
        qz += qv.x * z0[m] + qv.y * z0[m+1] + qv.z * z0[m+2] + qv.w * z0[m+3];
      }
    }
    dpart[4 + g][i] = qz;
  }
  __syncthreads();
  if (tid < 64)
    den[tid] = dpart[0][tid] + dpart[1][tid] + dpart[2][tid] + dpart[3][tid]
             + dpart[4][tid] + dpart[5][tid] + dpart[6][tid] + dpart[7][tid];
  // num: thread (g,d) owns rows i = g*16..+16, column d. Ks holds masked A.
  float acc[16];
#pragma unroll
  for (int ii = 0; ii < 16; ++ii) acc[ii] = 0.f;
  for (int j = 0; j < 64; j += 4) {
    float va = Vs[j][d], vb2 = Vs[j+1][d], vc = Vs[j+2][d], vd2 = Vs[j+3][d];
#pragma unroll
    for (int ii = 0; ii < 16; ++ii) {
      float4 av = *(const float4*)&Ks[g * 16 + ii][j];    // broadcast b128
      acc[ii] += av.x * va + av.y * vb2 + av.z * vc + av.w * vd2;
    }
  }
  if (c > 0) {
    for (int m = 0; m < 64; m += 4) {
      float sa = S0[(size_t)m * 64 + d];
      float sb2 = S0[(size_t)(m+1) * 64 + d];
      float sc = S0[(size_t)(m+2) * 64 + d];
      float sd2 = S0[(size_t)(m+3) * 64 + d];
#pragma unroll
      for (int ii = 0; ii < 16; ++ii) {
        float4 qv = *(const float4*)&Qs[g * 16 + ii][m];  // broadcast b128
        acc[ii] += qv.x * sa + qv.y * sb2 + qv.z * sc + qv.w * sd2;
      }
    }
  }
  __syncthreads();           // den[] visible
#pragma unroll
  for (int ii = 0; ii < 16; ++ii) {
    int i = g * 16 + ii;
    size_t off = ((size_t)(b * T_ + c * 64 + i) * D_) + h * 64 + d;
    out[off] = acc[ii] / (den[i] + 1e-16f);
  }
}

// ---------------------------------------------------------------------------
// x[row,:] += LayerNorm(a[row,:]) * g + b ; also writes bf16 mirror xb
// ---------------------------------------------------------------------------
__global__ __launch_bounds__(256) void ln_add_kernel(
    float* __restrict__ x, bf16* __restrict__ xb, const float* __restrict__ a,
    const float* __restrict__ g, const float* __restrict__ bta)
{
  int row = blockIdx.x;
  int tid = threadIdx.x;
  const float* ar = a + (size_t)row * D_;
  float v0 = ar[tid], v1 = ar[tid + 256];
  __shared__ float red[4];
  float w = v0 + v1;
  for (int o = 32; o > 0; o >>= 1) w += __shfl_down(w, o, 64);
  if ((tid & 63) == 0) red[tid >> 6] = w;
  __syncthreads();
  float mu = (red[0] + red[1] + red[2] + red[3]) * (1.f / 512.f);
  float d0 = v0 - mu, d1 = v1 - mu;
  __syncthreads();
  w = d0 * d0 + d1 * d1;
  for (int o = 32; o > 0; o >>= 1) w += __shfl_down(w, o, 64);
  if ((tid & 63) == 0) red[tid >> 6] = w;
  __syncthreads();
  float var = (red[0] + red[1] + red[2] + red[3]) * (1.f / 512.f);
  float rs = rsqrtf(var + 1e-5f);
  size_t xoff = (size_t)row * D_;
  float n0 = x[xoff + tid]       + d0 * rs * g[tid]       + bta[tid];
  float n1 = x[xoff + tid + 256] + d1 * rs * g[tid + 256] + bta[tid + 256];
  x[xoff + tid]        = n0;
  x[xoff + tid + 256]  = n1;
  xb[xoff + tid]       = __float2bfloat16(n0);
  xb[xoff + tid + 256] = __float2bfloat16(n1);
}

// ---------------------------------------------------------------------------
extern "C" void kernel_launch(void* const* d_in, const int* in_sizes, int n_in,
                              void* d_out, int out_size, void* d_ws, size_t ws_size,
                              hipStream_t stream) {
  const int*   tokens = (const int*)  d_in[0];
  const float* emb    = (const float*)d_in[1];
  const float* Wq     = (const float*)d_in[2];
  const float* bq     = (const float*)d_in[3];
  const float* Wk     = (const float*)d_in[4];
  const float* bk     = (const float*)d_in[5];
  const float* Wv     = (const float*)d_in[6];
  const float* bv     = (const float*)d_in[7];
  const float* rfs    = (const float*)d_in[8];
  const float* ln1g   = (const float*)d_in[9];
  const float* ln1b   = (const float*)d_in[10];
  const float* ln2g   = (const float*)d_in[11];
  const float* ln2b   = (const float*)d_in[12];
  const float* WU     = (const float*)d_in[13];
  const float* bU     = (const float*)d_in[14];
  const float* WV     = (const float*)d_in[15];
  const float* bV     = (const float*)d_in[16];
  const float* Wout   = (const float*)d_in[17];
  const float* bout   = (const float*)d_in[18];
  float* out = (float*)d_out;

  const size_t R = (size_t)BT_ * D_;          // 2,097,152 floats (8 MB)
  float* ws = (float*)d_ws;
  float* x  = ws + 0 * R;
  float* ab = ws + 1 * R;
  float* qb = ws + 2 * R;
  float* kb = ws + 3 * R;
  float* vb = ws + 4 * R;
  float* sb = ws + 5 * R;                     // chunk states (7.9 MB)
  bf16*  xb = (bf16*)(ws + 6 * R);            // R bf16 = 4 MB
  bf16*  hb = (bf16*)qb;                      // FFN hidden bf16 aliases qb+kb
  float* pb = ws + 16 * R;                    // split-K partials (<=32 MB)
  // transposed bf16 weights
  bf16* wT    = (bf16*)(ws + 6 * R + R / 2);
  bf16* WqT   = wT;                            // [L][D][D]  (RF-folded)
  bf16* WkT   = WqT + (size_t)2 * D_ * D_;     // (RF-folded)
  bf16* WvT   = WkT + (size_t)2 * D_ * D_;
  bf16* WUT   = WvT + (size_t)2 * D_ * D_;     // [L][FFN][D]
  bf16* WVT   = WUT + (size_t)2 * D_ * FFN_;   // [L][D][FFN]
  bf16* WoutT = WVT + (size_t)2 * D_ * FFN_;   // [VOCAB][D]
  float* bqf  = (float*)(WoutT + (size_t)VOCAB_ * D_);  // [L][D] folded bias
  float* bkf  = bqf + 2 * D_;

  // ---- weight prep: 2 launches ----
  rf_fold_w_kernel<<<dim3(8, 4, 4), 256, 0, stream>>>(Wq, Wk, rfs, WqT, WkT);
  prep_all_kernel<<<4740, 256, 0, stream>>>(
      Wv, WU, WV, Wout, WvT, WUT, WVT, WoutT, bq, bk, rfs, bqf, bkf);

  embed_pos_kernel<<<BT_, 512, 0, stream>>>(tokens, emb, x, xb);

  for (int l = 0; l < 2; ++l) {
    // batched QKV (q,k RF-folded, favor-exp fused): z = {q,k,v}, 384 blocks
    gemm_qkv<<<dim3(D_/128, BT_/128, 3), 256, 0, stream>>>(
        xb, wT, bqf, bkf, bv, qb, l);

    chunk_sum_kernel<<<16 * 31, 256, 0, stream>>>(kb, vb, sb);
    chunk_prefix_kernel<<<16 * 17, 256, 0, stream>>>(sb);
    chunk_attn_kernel<<<16 * NC_, 256, 0, stream>>>(qb, kb, vb, sb, ab);

    ln_add_kernel<<<BT_, 256, 0, stream>>>(x, xb, ab, ln1g + l*D_, ln1b + l*D_);

    gemm_mfma<<<dim3(FFN_/128, BT_/128), 256, 0, stream>>>(
        xb, WUT + (size_t)l*D_*FFN_, bU + l*FFN_, hb, BT_, FFN_, D_, 1);

    // FFN2 split-K: K=2048 -> 4 x 512, then fused reduce+bias+LN+residual
    gemm_splitk<<<dim3(D_/128, BT_/128, 4), 256, 0, stream>>>(
        hb, WVT + (size_t)l*FFN_*D_, pb, BT_, D_, FFN_, FFN_/4);
    reduce_ln_add_kernel<<<BT_, 256, 0, stream>>>(
        pb, bV + l*D_, x, xb, ln2g + l*D_, ln2b + l*D_);
  }

  // Wout split-K: K=512 -> 4 x 128, then reduce + bias
  gemm_splitk<<<dim3(VOCAB_/128, BT_/128, 4), 256, 0, stream>>>(
      xb, WoutT, pb, BT_, VOCAB_, D_, D_/4);
  reduce4_bias_kernel<<<(BT_*VOCAB_)/1024, 256, 0, stream>>>(
      pb, bout, out, BT_*VOCAB_, VOCAB_);
}

// Round 12
// 326.210 us; speedup vs baseline: 1.4576x; 1.1422x over previous
//
#include <hip/hip_runtime.h>
#include <hip/hip_bf16.h>
#include <math.h>

#define B_  2
#define T_  2048
#define D_  512
#define H_  8
#define HD_ 64
#define FFN_ 2048
#define VOCAB_ 256
#define BT_ (B_*T_)
#define NC_ 32            // chunks per (b,h), chunk size 64
#define CENT_ 4160        // floats per chunk state: 64*64 S + 64 z

typedef __attribute__((ext_vector_type(8))) short short8;
typedef __attribute__((ext_vector_type(4))) float float4v;
typedef __hip_bfloat16 bf16;

// async 16B/lane global->LDS DMA (wave-uniform LDS base + lane*16)
__device__ __forceinline__ void load16_lds(const void* g, void* l) {
  __builtin_amdgcn_global_load_lds(
      (const __attribute__((address_space(1))) unsigned int*)g,
      (__attribute__((address_space(3))) unsigned int*)l,
      16, 0, 0);
}

__device__ __forceinline__ unsigned short f2bf(float f) {
  bf16 h = __float2bfloat16(f);
  return __builtin_bit_cast(unsigned short, h);
}
__device__ __forceinline__ float bf2f(unsigned short u) {
  unsigned int i = ((unsigned int)u) << 16;
  return __builtin_bit_cast(float, i);
}

// ---------------------------------------------------------------------------
// Embedding + sinusoidal positional concat; writes fp32 x and bf16 mirror xb
// ---------------------------------------------------------------------------
__global__ __launch_bounds__(512) void embed_pos_kernel(
    const int* __restrict__ tokens, const float* __restrict__ emb,
    float* __restrict__ x, bf16* __restrict__ xb)
{
  int bt = blockIdx.x;          // b*T + t
  int t  = bt & (T_ - 1);
  int j  = threadIdx.x;
  float val;
  if (j < 256) {
    int tok = tokens[bt];
    val = emb[tok * 256 + j];
  } else {
    int jj = (j - 256) & 127;
    float f = expf(-(float)(2 * jj) * (9.210340371976184f / 256.0f));
    float arg = (float)t * f;
    val = (j < 384) ? sinf(arg) : cosf(arg);
  }
  size_t off = (size_t)bt * D_ + j;
  x[off]  = val;
  xb[off] = __float2bfloat16(val);
}

// ---------------------------------------------------------------------------
// All weight transposes (Wv, WU, WV, Wout) + rf_fold_b in ONE launch.
// ---------------------------------------------------------------------------
__global__ __launch_bounds__(256) void prep_all_kernel(
    const float* __restrict__ Wv, const float* __restrict__ WU,
    const float* __restrict__ WVp, const float* __restrict__ Wout,
    bf16* __restrict__ WvT, bf16* __restrict__ WUT,
    bf16* __restrict__ WVT, bf16* __restrict__ WoutT,
    const float* __restrict__ bq, const float* __restrict__ bk,
    const float* __restrict__ rfs, float* __restrict__ bqf,
    float* __restrict__ bkf)
{
  __shared__ float t[32][33];
  int id = blockIdx.x;
  if (id >= 4736) {                 // rf_fold_b, z = id - 4736
    int z = id - 4736;
    int l = z >> 1, side = z & 1;
    const float* b = (side ? bk : bq) + l * D_;
    float* bo = (side ? bkf : bqf) + l * D_;
    for (int n = threadIdx.x; n < D_; n += 256) {
      int h = n >> 6, j = n & 63;
      const float* R = rfs + ((size_t)l * H_ + h) * 4096;
      float acc = 0.f;
      for (int d = 0; d < 64; ++d) acc += b[h * 64 + d] * R[d * 64 + j];
      bo[n] = acc * 0.35355339059327373f;
    }
    return;
  }
  const float* W; bf16* Wt; int K, N, tx, ty;
  if (id < 512) {                   // Wv
    int l = id >> 8, tt = id & 255;
    W = Wv + (size_t)l * D_ * D_;  Wt = WvT + (size_t)l * D_ * D_;
    K = D_; N = D_; tx = tt & 15; ty = tt >> 4;
  } else if (id < 2560) {           // WU
    int tt = id - 512; int l = tt >> 10; tt &= 1023;
    W = WU + (size_t)l * D_ * FFN_;  Wt = WUT + (size_t)l * D_ * FFN_;
    K = D_; N = FFN_; tx = tt & 63; ty = tt >> 6;
  } else if (id < 4608) {           // WV
    int tt = id - 2560; int l = tt >> 10; tt &= 1023;
    W = WVp + (size_t)l * FFN_ * D_;  Wt = WVT + (size_t)l * FFN_ * D_;
    K = FFN_; N = D_; tx = tt & 15; ty = tt >> 4;
  } else {                          // Wout
    int tt = id - 4608;
    W = Wout;  Wt = WoutT;
    K = D_; N = VOCAB_; tx = tt & 7; ty = tt >> 3;
  }
  int n0 = tx * 32, k0 = ty * 32;
  int lx = threadIdx.x & 31, ly = threadIdx.x >> 5;
#pragma unroll
  for (int r = 0; r < 4; ++r)
    t[ly + 8 * r][lx] = W[(size_t)(k0 + ly + 8 * r) * N + n0 + lx];
  __syncthreads();
#pragma unroll
  for (int r = 0; r < 4; ++r)
    Wt[(size_t)(n0 + ly + 8 * r) * K + k0 + lx] = __float2bfloat16(t[lx][ly + 8 * r]);
}

// ---------------------------------------------------------------------------
// RF-fold weights (grid (8,4,4))
// ---------------------------------------------------------------------------
__global__ __launch_bounds__(256) void rf_fold_w_kernel(
    const float* __restrict__ Wq, const float* __restrict__ Wk,
    const float* __restrict__ rfs, bf16* __restrict__ WqT, bf16* __restrict__ WkT)
{
  int h = blockIdx.x, kq = blockIdx.y, z = blockIdx.z;
  int l = z >> 1, side = z & 1;
  const float* W = (side ? Wk : Wq) + (size_t)l * D_ * D_;
  bf16* WT = (side ? WkT : WqT) + (size_t)l * D_ * D_;
  const float* Rg = rfs + ((size_t)l * H_ + h) * 4096;
  __shared__ float Rl[64][65];
  __shared__ float Ws[128][65];
  int tid = threadIdx.x;
  for (int i = tid; i < 1024; i += 256) {
    float4 v4 = ((const float4*)Rg)[i];
    int d = i >> 4, j0 = (i & 15) * 4;
    Rl[d][j0] = v4.x; Rl[d][j0+1] = v4.y; Rl[d][j0+2] = v4.z; Rl[d][j0+3] = v4.w;
  }
  for (int i = tid; i < 2048; i += 256) {
    int r = i >> 4, c0 = (i & 15) * 4;
    float4 v4 = *(const float4*)&W[(size_t)(kq * 128 + r) * D_ + h * 64 + c0];
    Ws[r][c0] = v4.x; Ws[r][c0+1] = v4.y; Ws[r][c0+2] = v4.z; Ws[r][c0+3] = v4.w;
  }
  __syncthreads();
  int lane = tid & 63, w = tid >> 6;
  for (int kh = 0; kh < 2; ++kh) {
    int kk = kh * 64 + lane;
#pragma unroll 1
    for (int jj = 0; jj < 16; ++jj) {
      int j = w * 16 + jj;
      float acc = 0.f;
#pragma unroll 16
      for (int d = 0; d < 64; ++d) acc += Ws[kk][d] * Rl[d][j];
      WT[(size_t)(h * 64 + j) * D_ + kq * 128 + kk] =
          __float2bfloat16(acc * 0.35355339059327373f);
    }
  }
}

// ---------------------------------------------------------------------------
// MFMA GEMM core: 128x128 tile, BK=64, XOR-swizzled LDS, DMA staging.
// ---------------------------------------------------------------------------
__device__ __forceinline__ void mfma_core(
    const bf16* __restrict__ A, const bf16* __restrict__ Bt,
    int strideK, int kr, int row0, int col0, float4v acc[4][4])
{
  __shared__ short Al[128 * 64];
  __shared__ short Bl[128 * 64];
  int tid = threadIdx.x;
  int lane = tid & 63, w = tid >> 6;
  int wm = (w >> 1) * 64, wn = (w & 1) * 64;
  int quad = lane >> 4, l16 = lane & 15;

  int lr = lane >> 3;
  int ks = (((lane & 7) ^ lr)) * 8;
  const short* gA[4]; const short* gB[4];
  short* lA[4]; short* lB[4];
#pragma unroll
  for (int p = 0; p < 4; ++p) {
    int r = 32 * w + 8 * p;
    gA[p] = (const short*)A + (size_t)(row0 + r + lr) * strideK + ks;
    gB[p] = (const short*)Bt + (size_t)(col0 + r + lr) * strideK + ks;
    lA[p] = Al + r * 64;
    lB[p] = Bl + r * 64;
  }
#pragma unroll
  for (int p = 0; p < 4; ++p) {
    load16_lds(gA[p], lA[p]);
    load16_lds(gB[p], lB[p]);
  }

  for (int kt = 0; kt < kr; ++kt) {
    __syncthreads();
    short8 af[4][2], bfr[4][2];
#pragma unroll
    for (int mi = 0; mi < 4; ++mi) {
      int R = wm + mi * 16 + l16;
#pragma unroll
      for (int s = 0; s < 2; ++s) {
        int slot = (s * 4 + quad) ^ (R & 7);
        af[mi][s] = *(const short8*)&Al[R * 64 + slot * 8];
      }
    }
#pragma unroll
    for (int ni = 0; ni < 4; ++ni) {
      int R = wn + ni * 16 + l16;
#pragma unroll
      for (int s = 0; s < 2; ++s) {
        int slot = (s * 4 + quad) ^ (R & 7);
        bfr[ni][s] = *(const short8*)&Bl[R * 64 + slot * 8];
      }
    }
    __syncthreads();
    if (kt + 1 < kr) {
      int o = (kt + 1) * 64;
#pragma unroll
      for (int p = 0; p < 4; ++p) {
        load16_lds(gA[p] + o, lA[p]);
        load16_lds(gB[p] + o, lB[p]);
      }
    }
#pragma unroll
    for (int mi = 0; mi < 4; ++mi)
#pragma unroll
      for (int ni = 0; ni < 4; ++ni) {
        acc[mi][ni] = __builtin_amdgcn_mfma_f32_16x16x32_bf16(
            af[mi][0], bfr[ni][0], acc[mi][ni], 0, 0, 0);
        acc[mi][ni] = __builtin_amdgcn_mfma_f32_16x16x32_bf16(
            af[mi][1], bfr[ni][1], acc[mi][ni], 0, 0, 0);
      }
  }
}

// ---------------------------------------------------------------------------
// Generic GEMM: C = act(A @ Bt^T + bias). mode 0: fp32. mode 1: gelu->bf16.
// ---------------------------------------------------------------------------
__global__ __launch_bounds__(256) void gemm_mfma(
    const bf16* __restrict__ A, const bf16* __restrict__ Bt,
    const float* __restrict__ bias, void* __restrict__ Cout,
    int M, int N, int K, int mode)
{
  int lane = threadIdx.x & 63, w = threadIdx.x >> 6;
  int wm = (w >> 1) * 64, wn = (w & 1) * 64;
  int quad = lane >> 4, l16 = lane & 15;
  int row0 = blockIdx.y * 128, col0 = blockIdx.x * 128;
  float4v acc[4][4] = {};
  mfma_core(A, Bt, K, K >> 6, row0, col0, acc);
#pragma unroll
  for (int mi = 0; mi < 4; ++mi) {
#pragma unroll
    for (int ni = 0; ni < 4; ++ni) {
      int j = col0 + wn + ni * 16 + l16;
      float bj = bias[j];
#pragma unroll
      for (int r = 0; r < 4; ++r) {
        int i = row0 + wm + mi * 16 + quad * 4 + r;
        float v = acc[mi][ni][r] + bj;
        if (mode == 1) {
          v = 0.5f * v * (1.0f + erff(v * 0.7071067811865475f));
          ((bf16*)Cout)[(size_t)i * N + j] = __float2bfloat16(v);
        } else {
          ((float*)Cout)[(size_t)i * N + j] = v;
        }
      }
    }
  }
}

// ---------------------------------------------------------------------------
// Batched QKV GEMM with fused FAVOR exp for q,k: blockIdx.z = {q,k,v}.
// Output bf16 (consumed by MFMA chunk kernels).
// ---------------------------------------------------------------------------
__global__ __launch_bounds__(256) void gemm_qkv(
    const bf16* __restrict__ A, const bf16* __restrict__ wT,
    const float* __restrict__ bqf, const float* __restrict__ bkf,
    const float* __restrict__ bv, bf16* __restrict__ outb, int l)
{
  int z = blockIdx.z;
  const bf16* Bt = wT + ((size_t)z * 2 + l) * D_ * D_;
  const float* bias = (z == 0 ? bqf : (z == 1 ? bkf : bv)) + l * D_;
  bf16* Cout = outb + (size_t)z * BT_ * D_;
  int lane = threadIdx.x & 63, w = threadIdx.x >> 6;
  int wm = (w >> 1) * 64, wn = (w & 1) * 64;
  int quad = lane >> 4, l16 = lane & 15;
  int row0 = blockIdx.y * 128, col0 = blockIdx.x * 128;
  float4v acc[4][4] = {};
  mfma_core(A, Bt, D_, D_ >> 6, row0, col0, acc);
  if (z < 2) {
#pragma unroll
    for (int mi = 0; mi < 4; ++mi) {
      float vres[4][4];
      float sq[4] = {0.f, 0.f, 0.f, 0.f};
#pragma unroll
      for (int ni = 0; ni < 4; ++ni) {
        int j = col0 + wn + ni * 16 + l16;
        float bj = bias[j];
#pragma unroll
        for (int r = 0; r < 4; ++r) {
          float v = acc[mi][ni][r] + bj;
          vres[ni][r] = v;
          sq[r] += v * v;
        }
      }
#pragma unroll
      for (int r = 0; r < 4; ++r) {
        float s = sq[r];
        s += __shfl_xor(s, 1, 64);
        s += __shfl_xor(s, 2, 64);
        s += __shfl_xor(s, 4, 64);
        s += __shfl_xor(s, 8, 64);
        sq[r] = s;
      }
#pragma unroll
      for (int ni = 0; ni < 4; ++ni) {
        int j = col0 + wn + ni * 16 + l16;
#pragma unroll
        for (int r = 0; r < 4; ++r) {
          int i = row0 + wm + mi * 16 + quad * 4 + r;
          Cout[(size_t)i * D_ + j] =
              __float2bfloat16(__expf(vres[ni][r] - sq[r] * (1.0f / 128.0f)));
        }
      }
    }
  } else {
#pragma unroll
    for (int mi = 0; mi < 4; ++mi) {
#pragma unroll
      for (int ni = 0; ni < 4; ++ni) {
        int j = col0 + wn + ni * 16 + l16;
        float bj = bias[j];
#pragma unroll
        for (int r = 0; r < 4; ++r) {
          int i = row0 + wm + mi * 16 + quad * 4 + r;
          Cout[(size_t)i * D_ + j] = __float2bfloat16(acc[mi][ni][r] + bj);
        }
      }
    }
  }
}

// ---------------------------------------------------------------------------
// Split-K GEMM: P[s][M][N] = A[:, s*KS:(s+1)*KS] @ slice. s = blockIdx.z.
// ---------------------------------------------------------------------------
__global__ __launch_bounds__(256) void gemm_splitk(
    const bf16* __restrict__ A, const bf16* __restrict__ Bt,
    float* __restrict__ P, int M, int N, int K, int KS)
{
  int s = blockIdx.z;
  int lane = threadIdx.x & 63, w = threadIdx.x >> 6;
  int wm = (w >> 1) * 64, wn = (w & 1) * 64;
  int quad = lane >> 4, l16 = lane & 15;
  int row0 = blockIdx.y * 128, col0 = blockIdx.x * 128;
  float4v acc[4][4] = {};
  mfma_core((const bf16*)((const short*)A + s * KS),
            (const bf16*)((const short*)Bt + s * KS),
            K, KS >> 6, row0, col0, acc);
  float* Ps = P + (size_t)s * M * N;
#pragma unroll
  for (int mi = 0; mi < 4; ++mi) {
#pragma unroll
    for (int ni = 0; ni < 4; ++ni) {
      int j = col0 + wn + ni * 16 + l16;
#pragma unroll
      for (int r = 0; r < 4; ++r) {
        int i = row0 + wm + mi * 16 + quad * 4 + r;
        Ps[(size_t)i * N + j] = acc[mi][ni][r];
      }
    }
  }
}

// ---------------------------------------------------------------------------
// Final-output reduce: C = bias + sum of 4 split partials
// ---------------------------------------------------------------------------
__global__ __launch_bounds__(256) void reduce4_bias_kernel(
    const float* __restrict__ P, const float* __restrict__ bias,
    float* __restrict__ C, int MN, int N)
{
  int idx = (blockIdx.x * 256 + threadIdx.x) * 4;
  float4 s0 = *(const float4*)&P[idx];
  float4 s1 = *(const float4*)&P[idx + MN];
  float4 s2 = *(const float4*)&P[idx + 2 * MN];
  float4 s3 = *(const float4*)&P[idx + 3 * MN];
  float4 b  = *(const float4*)&bias[idx & (N - 1)];
  float4 r;
  r.x = s0.x + s1.x + s2.x + s3.x + b.x;
  r.y = s0.y + s1.y + s2.y + s3.y + b.y;
  r.z = s0.z + s1.z + s2.z + s3.z + b.z;
  r.w = s0.w + s1.w + s2.w + s3.w + b.w;
  *(float4*)&C[idx] = r;
}

// ---------------------------------------------------------------------------
// Fused split-K reduce + bias + LayerNorm + residual add (FFN2 epilogue)
// ---------------------------------------------------------------------------
__global__ __launch_bounds__(256) void reduce_ln_add_kernel(
    const float* __restrict__ P, const float* __restrict__ bias,
    float* __restrict__ x, bf16* __restrict__ xb,
    const float* __restrict__ g, const float* __restrict__ bta)
{
  const int MN = BT_ * D_;
  int row = blockIdx.x;
  int tid = threadIdx.x;
  size_t base = (size_t)row * D_;
  float v0 = P[base + tid] + P[MN + base + tid] + P[2 * MN + base + tid]
           + P[3 * MN + base + tid] + bias[tid];
  float v1 = P[base + tid + 256] + P[MN + base + tid + 256]
           + P[2 * MN + base + tid + 256] + P[3 * MN + base + tid + 256]
           + bias[tid + 256];
  __shared__ float red[4];
  float w = v0 + v1;
  for (int o = 32; o > 0; o >>= 1) w += __shfl_down(w, o, 64);
  if ((tid & 63) == 0) red[tid >> 6] = w;
  __syncthreads();
  float mu = (red[0] + red[1] + red[2] + red[3]) * (1.f / 512.f);
  float d0 = v0 - mu, d1 = v1 - mu;
  __syncthreads();
  w = d0 * d0 + d1 * d1;
  for (int o = 32; o > 0; o >>= 1) w += __shfl_down(w, o, 64);
  if ((tid & 63) == 0) red[tid >> 6] = w;
  __syncthreads();
  float var = (red[0] + red[1] + red[2] + red[3]) * (1.f / 512.f);
  float rs = rsqrtf(var + 1e-5f);
  float n0 = x[base + tid]       + d0 * rs * g[tid]       + bta[tid];
  float n1 = x[base + tid + 256] + d1 * rs * g[tid + 256] + bta[tid + 256];
  x[base + tid]        = n0;
  x[base + tid + 256]  = n1;
  xb[base + tid]       = __float2bfloat16(n0);
  xb[base + tid + 256] = __float2bfloat16(n1);
}

// ---------------------------------------------------------------------------
// Pass 1 (MFMA): per-chunk sums. S[m][d] = sum_t Kf[t][m] V[t][d].
// Transpose-gather bf16 into LDS KT[m][t], VT[d][t] (XOR-swizzled chunks),
// then one 64x64x64 MFMA block. z via VALU from KT.
// ---------------------------------------------------------------------------
__global__ __launch_bounds__(256) void chunk_sum_kernel(
    const bf16* __restrict__ kf, const bf16* __restrict__ vf,
    float* __restrict__ buf)
{
  int bh = blockIdx.x / 31;
  int c  = blockIdx.x % 31;
  int b = bh >> 3, h = bh & 7;
  __shared__ short KT[64 * 64];   // [m][t] swizzled
  __shared__ short VT[64 * 64];   // [d][t] swizzled
  __shared__ float zpart[4][64];
  int tid = threadIdx.x;
  int m = tid & 63, g = tid >> 6;
  const size_t rowbase = ((size_t)(b * T_ + c * 64)) * D_ + h * 64;
#pragma unroll
  for (int cc0 = 0; cc0 < 2; ++cc0) {
    int cc = g + cc0 * 4;
    short8 kk, vv;
#pragma unroll
    for (int u = 0; u < 8; ++u) {
      size_t off = rowbase + (size_t)(cc * 8 + u) * D_ + m;
      kk[u] = ((const short*)kf)[off];
      vv[u] = ((const short*)vf)[off];
    }
    int slot = cc ^ (m & 7);
    *(short8*)&KT[m * 64 + slot * 8] = kk;
    *(short8*)&VT[m * 64 + slot * 8] = vv;
  }
  __syncthreads();
  int quad = (tid & 63) >> 4, l16 = tid & 15;
  int ar = g * 16 + l16;          // A row (m), wave g band
  short8 afr[2];
#pragma unroll
  for (int s = 0; s < 2; ++s)
    afr[s] = *(const short8*)&KT[ar * 64 + ((s * 4 + quad) ^ (ar & 7)) * 8];
  float4v acc[4] = {};
#pragma unroll
  for (int nd = 0; nd < 4; ++nd) {
    int br = nd * 16 + l16;
#pragma unroll
    for (int s = 0; s < 2; ++s) {
      short8 bfr = *(const short8*)&VT[br * 64 + ((s * 4 + quad) ^ (br & 7)) * 8];
      acc[nd] = __builtin_amdgcn_mfma_f32_16x16x32_bf16(afr[s], bfr, acc[nd], 0, 0, 0);
    }
  }
  // z partials from KT
  float zp = 0.f;
#pragma unroll
  for (int cc0 = 0; cc0 < 2; ++cc0) {
    int cc = g + cc0 * 4;
    short8 kk = *(const short8*)&KT[m * 64 + (cc ^ (m & 7)) * 8];
#pragma unroll
    for (int u = 0; u < 8; ++u) zp += bf2f((unsigned short)kk[u]);
  }
  zpart[g][m] = zp;
  size_t bo = (size_t)(bh * 31 + c) * CENT_;
#pragma unroll
  for (int nd = 0; nd < 4; ++nd)
#pragma unroll
    for (int r = 0; r < 4; ++r)
      buf[bo + (size_t)(g * 16 + quad * 4 + r) * 64 + nd * 16 + l16] = acc[nd][r];
  __syncthreads();
  if (tid < 64)
    buf[bo + 4096 + tid] = zpart[0][tid] + zpart[1][tid] + zpart[2][tid] + zpart[3][tid];
}

// ---------------------------------------------------------------------------
// Pass 2: inclusive scan over 31 chunk states per (b,h)
// ---------------------------------------------------------------------------
__global__ __launch_bounds__(256) void chunk_prefix_kernel(float* __restrict__ buf)
{
  int bh = blockIdx.x / 17;
  int grp = blockIdx.x % 17;
  int e = grp * 256 + threadIdx.x;
  if (e >= CENT_) return;
  size_t base = (size_t)bh * 31 * CENT_ + e;
  float vals[31];
#pragma unroll
  for (int c = 0; c < 31; ++c) vals[c] = buf[base + (size_t)c * CENT_];
  float run = 0.f;
#pragma unroll
  for (int c = 0; c < 31; ++c) {
    run += vals[c];
    buf[base + (size_t)c * CENT_] = run;
  }
}

// ---------------------------------------------------------------------------
// Pass 3 (MFMA): per-chunk attention.
// Phase 1: A = Qf Kf^T (natural layouts, DMA-staged). Mask + rowsum in
// C-frags; masked A -> bf16 into Ks' LDS. Phase 2: num = As V + Qf S0
// (VT, S0T transpose-gathered). den = rowsum + Qf.z0.
// ---------------------------------------------------------------------------
__global__ __launch_bounds__(256) void chunk_attn_kernel(
    const bf16* __restrict__ qf, const bf16* __restrict__ kf,
    const bf16* __restrict__ vf, const float* __restrict__ buf,
    float* __restrict__ out)
{
  int bh = blockIdx.x >> 5;
  int ck = blockIdx.x & 31;
  int b = bh >> 3, h = bh & 7;
  __shared__ short Qs[64 * 64];   // [t][m] natural swizzled
  __shared__ short Ks[64 * 64];   // [t][m]; reused as As[i][j] after phase 1
  __shared__ short VT[64 * 64];   // [d][t]
  __shared__ short S0T[64 * 64];  // [d][m]
  __shared__ float z0[64];
  __shared__ float dlds[64];
  __shared__ float dpartA[64];
  __shared__ float dpartQ[4][64];
  int tid = threadIdx.x;
  int lane = tid & 63, w = tid >> 6;
  int quad = lane >> 4, l16 = lane & 15;
  const size_t rb = ((size_t)(b * T_ + ck * 64)) * D_ + h * 64;

  // --- staging ---
  {
    int lr = lane >> 3;
    int fc = (lane & 7) ^ lr;
#pragma unroll
    for (int seg = 0; seg < 2; ++seg) {
      int r = 16 * w + 8 * seg;
      load16_lds((const short*)qf + rb + (size_t)(r + lr) * D_ + fc * 8, &Qs[r * 64]);
      load16_lds((const short*)kf + rb + (size_t)(r + lr) * D_ + fc * 8, &Ks[r * 64]);
    }
    int d = lane;
    const float* S0 = buf + (size_t)(bh * 31 + (ck > 0 ? ck - 1 : 0)) * CENT_;
#pragma unroll
    for (int cc0 = 0; cc0 < 2; ++cc0) {
      int cc = w + cc0 * 4;
      short8 vv, ss;
#pragma unroll
      for (int u = 0; u < 8; ++u) {
        vv[u] = ((const short*)vf)[rb + (size_t)(cc * 8 + u) * D_ + d];
        ss[u] = (ck > 0) ? (short)f2bf(S0[(size_t)(cc * 8 + u) * 64 + d]) : (short)0;
      }
      int slot = cc ^ (d & 7);
      *(short8*)&VT[d * 64 + slot * 8] = vv;
      *(short8*)&S0T[d * 64 + slot * 8] = ss;
    }
    if (tid < 64) z0[tid] = (ck > 0) ? S0[4096 + tid] : 0.f;
  }
  __syncthreads();

  // --- phase 1: A[i][j] = sum_m Qf[i][m] Kf[j][m], i-band = wave w ---
  float4v pacc[4] = {};
  {
    int ar = 16 * w + l16;
    short8 afr[2];
#pragma unroll
    for (int s = 0; s < 2; ++s)
      afr[s] = *(const short8*)&Qs[ar * 64 + ((s * 4 + quad) ^ (ar & 7)) * 8];
#pragma unroll
    for (int nj = 0; nj < 4; ++nj) {
      int br = nj * 16 + l16;
#pragma unroll
      for (int s = 0; s < 2; ++s) {
        short8 bfr = *(const short8*)&Ks[br * 64 + ((s * 4 + quad) ^ (br & 7)) * 8];
        pacc[nj] = __builtin_amdgcn_mfma_f32_16x16x32_bf16(afr[s], bfr, pacc[nj], 0, 0, 0);
      }
    }
  }
  // den partial: qz[i] over m-chunks {w, w+4}
  {
    int i = lane;
    float qz = 0.f;
#pragma unroll
    for (int cc0 = 0; cc0 < 2; ++cc0) {
      int cc = w + cc0 * 4;
      short8 qq = *(const short8*)&Qs[i * 64 + (cc ^ (i & 7)) * 8];
#pragma unroll
      for (int u = 0; u < 8; ++u) qz += bf2f((unsigned short)qq[u]) * z0[cc * 8 + u];
    }
    dpartQ[w][i] = qz;
  }
  __syncthreads();               // all Ks frag reads done

  // --- mask + rowsum + write As (into Ks) ---
  {
    float rs[4] = {0.f, 0.f, 0.f, 0.f};
#pragma unroll
    for (int nj = 0; nj < 4; ++nj) {
#pragma unroll
      for (int r = 0; r < 4; ++r) {
        int i = 16 * w + quad * 4 + r;
        int j = nj * 16 + l16;
        float val = (j <= i) ? pacc[nj][r] : 0.f;
        rs[r] += val;
        ((unsigned short*)Ks)[i * 64 + ((j >> 3) ^ (i & 7)) * 8 + (j & 7)] = f2bf(val);
      }
    }
#pragma unroll
    for (int r = 0; r < 4; ++r) {
      float s = rs[r];
      s += __shfl_xor(s, 1, 64);
      s += __shfl_xor(s, 2, 64);
      s += __shfl_xor(s, 4, 64);
      s += __shfl_xor(s, 8, 64);
      rs[r] = s;
    }
    if (l16 == 0) {
#pragma unroll
      for (int r = 0; r < 4; ++r) dpartA[16 * w + quad * 4 + r] = rs[r];
    }
  }
  __syncthreads();
  if (tid < 64)
    dlds[tid] = dpartA[tid] + dpartQ[0][tid] + dpartQ[1][tid]
              + dpartQ[2][tid] + dpartQ[3][tid];

  // --- phase 2: num = As.V^T' + Qf.S0 (i-band w, d-bands nd) ---
  float4v acc[4] = {};
  {
    int ar = 16 * w + l16;
    short8 aA[2], aQ[2];
#pragma unroll
    for (int s = 0; s < 2; ++s) {
      aA[s] = *(const short8*)&Ks[ar * 64 + ((s * 4 + quad) ^ (ar & 7)) * 8];
      aQ[s] = *(const short8*)&Qs[ar * 64 + ((s * 4 + quad) ^ (ar & 7)) * 8];
    }
#pragma unroll
    for (int nd = 0; nd < 4; ++nd) {
      int br = nd * 16 + l16;
#pragma unroll
      for (int s = 0; s < 2; ++s) {
        short8 bV = *(const short8*)&VT[br * 64 + ((s * 4 + quad) ^ (br & 7)) * 8];
        acc[nd] = __builtin_amdgcn_mfma_f32_16x16x32_bf16(aA[s], bV, acc[nd], 0, 0, 0);
        short8 bS = *(const short8*)&S0T[br * 64 + ((s * 4 + quad) ^ (br & 7)) * 8];
        acc[nd] = __builtin_amdgcn_mfma_f32_16x16x32_bf16(aQ[s], bS, acc[nd], 0, 0, 0);
      }
    }
  }
  __syncthreads();               // dlds visible
#pragma unroll
  for (int nd = 0; nd < 4; ++nd)
#pragma unroll
    for (int r = 0; r < 4; ++r) {
      int i = 16 * w + quad * 4 + r;
      int d = nd * 16 + l16;
      out[((size_t)(b * T_ + ck * 64 + i)) * D_ + h * 64 + d] =
          acc[nd][r] / (dlds[i] + 1e-16f);
    }
}

// ---------------------------------------------------------------------------
// x[row,:] += LayerNorm(a[row,:]) * g + b ; also writes bf16 mirror xb
// ---------------------------------------------------------------------------
__global__ __launch_bounds__(256) void ln_add_kernel(
    float* __restrict__ x, bf16* __restrict__ xb, const float* __restrict__ a,
    const float* __restrict__ g, const float* __restrict__ bta)
{
  int row = blockIdx.x;
  int tid = threadIdx.x;
  const float* ar = a + (size_t)row * D_;
  float v0 = ar[tid], v1 = ar[tid + 256];
  __shared__ float red[4];
  float w = v0 + v1;
  for (int o = 32; o > 0; o >>= 1) w += __shfl_down(w, o, 64);
  if ((tid & 63) == 0) red[tid >> 6] = w;
  __syncthreads();
  float mu = (red[0] + red[1] + red[2] + red[3]) * (1.f / 512.f);
  float d0 = v0 - mu, d1 = v1 - mu;
  __syncthreads();
  w = d0 * d0 + d1 * d1;
  for (int o = 32; o > 0; o >>= 1) w += __shfl_down(w, o, 64);
  if ((tid & 63) == 0) red[tid >> 6] = w;
  __syncthreads();
  float var = (red[0] + red[1] + red[2] + red[3]) * (1.f / 512.f);
  float rs = rsqrtf(var + 1e-5f);
  size_t xoff = (size_t)row * D_;
  float n0 = x[xoff + tid]       + d0 * rs * g[tid]       + bta[tid];
  float n1 = x[xoff + tid + 256] + d1 * rs * g[tid + 256] + bta[tid + 256];
  x[xoff + tid]        = n0;
  x[xoff + tid + 256]  = n1;
  xb[xoff + tid]       = __float2bfloat16(n0);
  xb[xoff + tid + 256] = __float2bfloat16(n1);
}

// ---------------------------------------------------------------------------
extern "C" void kernel_launch(void* const* d_in, const int* in_sizes, int n_in,
                              void* d_out, int out_size, void* d_ws, size_t ws_size,
                              hipStream_t stream) {
  const int*   tokens = (const int*)  d_in[0];
  const float* emb    = (const float*)d_in[1];
  const float* Wq     = (const float*)d_in[2];
  const float* bq     = (const float*)d_in[3];
  const float* Wk     = (const float*)d_in[4];
  const float* bk     = (const float*)d_in[5];
  const float* Wv     = (const float*)d_in[6];
  const float* bv     = (const float*)d_in[7];
  const float* rfs    = (const float*)d_in[8];
  const float* ln1g   = (const float*)d_in[9];
  const float* ln1b   = (const float*)d_in[10];
  const float* ln2g   = (const float*)d_in[11];
  const float* ln2b   = (const float*)d_in[12];
  const float* WU     = (const float*)d_in[13];
  const float* bU     = (const float*)d_in[14];
  const float* WV     = (const float*)d_in[15];
  const float* bV     = (const float*)d_in[16];
  const float* Wout   = (const float*)d_in[17];
  const float* bout   = (const float*)d_in[18];
  float* out = (float*)d_out;

  const size_t R = (size_t)BT_ * D_;          // 2,097,152 floats (8 MB)
  float* ws = (float*)d_ws;
  float* x  = ws;                             // [0, R)
  float* ab = ws + R;                         // [R, 2R)
  float* sb = ws + 2 * R;                     // [2R, 3R) chunk states (7.9 MB)
  bf16*  qb = (bf16*)(ws + 3 * R);            // [3R, 3.5R) bf16 BT x D
  bf16*  kb = (bf16*)(ws + 3 * R + R / 2);    // [3.5R, 4R)
  bf16*  vb = (bf16*)(ws + 4 * R);            // [4R, 4.5R)
  bf16*  xb = (bf16*)(ws + 4 * R + R / 2);    // [4.5R, 5R)
  bf16*  hb = (bf16*)(ws + 5 * R);            // [5R, 7R) bf16 BT x FFN
  float* pb = ws + 7 * R;                     // [7R, 11R) split-K partials
  bf16*  wT = (bf16*)(ws + 11 * R);           // weights
  bf16* WqT   = wT;                            // [L][D][D] (RF-folded)
  bf16* WkT   = WqT + (size_t)2 * D_ * D_;
  bf16* WvT   = WkT + (size_t)2 * D_ * D_;
  bf16* WUT   = WvT + (size_t)2 * D_ * D_;     // [L][FFN][D]
  bf16* WVT   = WUT + (size_t)2 * D_ * FFN_;   // [L][D][FFN]
  bf16* WoutT = WVT + (size_t)2 * D_ * FFN_;   // [VOCAB][D]
  float* bqf  = (float*)(WoutT + (size_t)VOCAB_ * D_);
  float* bkf  = bqf + 2 * D_;

  // ---- weight prep ----
  rf_fold_w_kernel<<<dim3(8, 4, 4), 256, 0, stream>>>(Wq, Wk, rfs, WqT, WkT);
  prep_all_kernel<<<4740, 256, 0, stream>>>(
      Wv, WU, WV, Wout, WvT, WUT, WVT, WoutT, bq, bk, rfs, bqf, bkf);

  embed_pos_kernel<<<BT_, 512, 0, stream>>>(tokens, emb, x, xb);

  for (int l = 0; l < 2; ++l) {
    gemm_qkv<<<dim3(D_/128, BT_/128, 3), 256, 0, stream>>>(
        xb, wT, bqf, bkf, bv, qb, l);

    chunk_sum_kernel<<<16 * 31, 256, 0, stream>>>(kb, vb, sb);
    chunk_prefix_kernel<<<16 * 17, 256, 0, stream>>>(sb);
    chunk_attn_kernel<<<16 * NC_, 256, 0, stream>>>(qb, kb, vb, sb, ab);

    ln_add_kernel<<<BT_, 256, 0, stream>>>(x, xb, ab, ln1g + l*D_, ln1b + l*D_);

    gemm_mfma<<<dim3(FFN_/128, BT_/128), 256, 0, stream>>>(
        xb, WUT + (size_t)l*D_*FFN_, bU + l*FFN_, hb, BT_, FFN_, D_, 1);

    gemm_splitk<<<dim3(D_/128, BT_/128, 4), 256, 0, stream>>>(
        hb, WVT + (size_t)l*FFN_*D_, pb, BT_, D_, FFN_, FFN_/4);
    reduce_ln_add_kernel<<<BT_, 256, 0, stream>>>(
        pb, bV + l*D_, x, xb, ln2g + l*D_, ln2b + l*D_);
  }

  gemm_splitk<<<dim3(VOCAB_/128, BT_/128, 4), 256, 0, stream>>>(
      xb, WoutT, pb, BT_, VOCAB_, D_, D_/4);
  reduce4_bias_kernel<<<(BT_*VOCAB_)/1024, 256, 0, stream>>>(
      pb, bout, out, BT_*VOCAB_, VOCAB_);
}